// Round 12
// baseline (563.136 us; speedup 1.0000x reference)
//
#include <hip/hip_runtime.h>

// MLA prefill: B=2, S=2048, DIM=2048, NH=16, Q_LORA=1536, KV_LORA=512,
// NOPE=128, ROPE=64, VHD=128, QK_HD=192.
// I/O dtype: FP32. Internal: bf16 MFMA.
//
// Round-12: attn V^T staging via cross-quad register transpose. The 32
// scalar ds_write_u16/thread/iter were the source of the 15.7M
// SQ_LDS_BANK_CONFLICT cycles, serialized between B1 and B2 on every
// wave. Quad-siblings {l16,l16+16,l16+32,l16+48} hold rows r0..r0+3 at
// the same cols; in the swizzled V^T layout those 4 row-values per col
// are CONTIGUOUS (rs const, rl=rl0..rl0+3). Two shfl_xor butterflies
// (16,32) = 4x4 u32 transpose -> each lane stores 2 cols x 4 rows as two
// 8B writes. Same final layout; PV reads untouched. 32 scalar->8 vector
// LDS writes/thread/iter. Rest byte-identical to r11 (539us best).
//
// WS plan (merged path, high-water 123,994,112 B):
//   qn    @ 0           [4096,1536]
//   kvn   @ 12,582,912  [4096, 576]  (cols 512..575 raw pe)
//   kpe   @ 17,301,504  [4096,  64]
//   qbA   @ 17,825,792  [4096,1536]  heads 0..7, pre-scaled by SCALE
//   kvB   @ 30,408,704  [4096,2048]  heads 8..15 (k_nope128|v128)
//   ao    @ 47,185,920  [4096,2048]
//   xb    @ 63,963,136  [4096,2048]  bf16 of x;  kvA reuses this slot
//   wqab  @ 80,740,352  [1536,2048]  bf16 weights
//   wkvab @ 87,031,808  [576,2048]
//   wqbb  @ 89,391,104  [2*1536,1536]
//   wkvbw @ 98,828,288  [2*2048,512]
//   wob   @103,022,592  [2048,2048]
//   qbB   @111,411,200  [4096,1536]  heads 8..15
// Fallbacks: ws>=111,411,200 -> round-4 path; else round-2 legacy path.

typedef __bf16 bf16x8 __attribute__((ext_vector_type(8)));
typedef float f32x4 __attribute__((ext_vector_type(4)));
typedef unsigned short u16;
typedef unsigned int u32;

#define SEQ 2048
#define SCALE 0.07216878364870323f  // 192^-0.5
#define NEGBIG -30000.0f            // expf underflows to exactly 0

__device__ __forceinline__ float b2f(u16 u) {
  union { unsigned u; float f; } c; c.u = ((unsigned)u) << 16; return c.f;
}
__device__ __forceinline__ u16 f2b(float f) {  // RNE fp32->bf16
  union { float f; unsigned u; } c; c.f = f;
  unsigned r = (c.u + 0x7fffu + ((c.u >> 16) & 1u)) >> 16;
  return (u16)r;
}
__device__ __forceinline__ uint4 pack8(float4 a, float4 b) {
  union { uint4 v; u16 e[8]; } t;
  t.e[0] = f2b(a.x); t.e[1] = f2b(a.y); t.e[2] = f2b(a.z); t.e[3] = f2b(a.w);
  t.e[4] = f2b(b.x); t.e[5] = f2b(b.y); t.e[6] = f2b(b.z); t.e[7] = f2b(b.w);
  return t.v;
}

// async 16B global -> LDS (HW writes lane's 16B to ldsbase + lane*16)
#define GLOAD_LDS16(gsrc, ldst)                                              \
  __builtin_amdgcn_global_load_lds(                                          \
      (const __attribute__((address_space(1))) unsigned int*)(gsrc),         \
      (__attribute__((address_space(3))) unsigned int*)(ldst), 16, 0, 0)

// ---------------------------------------------------------------------------
// fp32 -> bf16 bulk convert (n8 = element_count / 8)
// ---------------------------------------------------------------------------
__global__ void cvt_kernel(const float* __restrict__ src, u16* __restrict__ dst,
                           long n8) {
  long i = (long)blockIdx.x * 256 + threadIdx.x;
  long stride = (long)gridDim.x * 256;
  for (; i < n8; i += stride) {
    const float4* s = (const float4*)(src + i * 8);
    float4 a = s[0], b = s[1];
    *(uint4*)(dst + i * 8) = pack8(a, b);
  }
}

// ---------------------------------------------------------------------------
// gemm_lds (r7-verified structure): out[4096,Ntot] = X @ W^T + bias, split
// across two destination buffers at col N0 (out0 cols [0,N0), stride N0;
// out1 cols [N0,Ntot), stride Ntot-N0). Requires N%128==0, K%64==0.
// 128x128 tile, BK=64, 4 waves 2x2 (acc 4x4), double-buffered
// global_load_lds staging, ONE barrier per K-step.
// LDS: XOR-swizzled LDS[r][c ^ ((r&7)*8)] = M[r][k0+c] via linear
// gload_lds dest + pre-swizzled global source col ((lane&7)^(lane>>3))*8;
// fragment ds_read applies the same XOR (identity round-trip).
// ---------------------------------------------------------------------------
template <int OF>
__global__ __launch_bounds__(256) void gemm_lds_kernel(
    const u16* __restrict__ X, int lda, const u16* __restrict__ W,
    const float* __restrict__ bias, void* __restrict__ out0,
    void* __restrict__ out1, int N0, int Ntot, int K, float oscale) {
  __shared__ alignas(16) u16 As[2][128 * 64];
  __shared__ alignas(16) u16 Bs[2][128 * 64];
  const int tid = threadIdx.x;
  const int wave = tid >> 6, lane = tid & 63;
  const int quad = lane >> 4, l16 = lane & 15;
  const int wr = (wave >> 1) * 64, wc = (wave & 1) * 64;
  const int bm = blockIdx.x * 128, bn = blockIdx.y * 128;
  const int srow0 = wave * 32 + (lane >> 3);          // + p*8
  const int gcol = ((lane & 7) ^ (lane >> 3)) * 8;    // pre-swizzled source col

  f32x4 acc[4][4] = {};

  auto stage = [&](int buf, int k0) {
#pragma unroll
    for (int p = 0; p < 4; ++p) {
      int row = srow0 + p * 8;
      const u16* ga = X + (size_t)(bm + row) * lda + k0 + gcol;
      const u16* gb = W + (size_t)(bn + row) * K + k0 + gcol;
      char* la = (char*)(&As[buf][0]) + (wave * 4 + p) * 1024;
      char* lb = (char*)(&Bs[buf][0]) + (wave * 4 + p) * 1024;
      GLOAD_LDS16(ga, la);
      GLOAD_LDS16(gb, lb);
    }
  };

  const int nk = K >> 6;
  stage(0, 0);
  int cur = 0;
  for (int kt = 0; kt < nk; ++kt) {
    __syncthreads();  // vmcnt drain: buf[cur] staged; prev readers of buf[cur^1] done
    if (kt + 1 < nk) stage(cur ^ 1, (kt + 1) * 64);  // flies under MFMA below
    const u16* as = &As[cur][0];
    const u16* bs = &Bs[cur][0];
#pragma unroll
    for (int kk = 0; kk < 64; kk += 32) {
      const int cs = (kk + quad * 8) ^ ((l16 & 7) * 8);
      bf16x8 a[4], b[4];
#pragma unroll
      for (int i = 0; i < 4; ++i)
        a[i] = *(const bf16x8*)(as + (wr + i * 16 + l16) * 64 + cs);
#pragma unroll
      for (int j = 0; j < 4; ++j)
        b[j] = *(const bf16x8*)(bs + (wc + j * 16 + l16) * 64 + cs);
#pragma unroll
      for (int i = 0; i < 4; ++i)
#pragma unroll
        for (int j = 0; j < 4; ++j)
          acc[i][j] = __builtin_amdgcn_mfma_f32_16x16x32_bf16(a[i], b[j], acc[i][j], 0, 0, 0);
    }
    cur ^= 1;
  }

  const int N1 = Ntot - N0;
#pragma unroll
  for (int i = 0; i < 4; ++i)
#pragma unroll
    for (int j = 0; j < 4; ++j) {
      int col = bn + wc + j * 16 + l16;
      float bv = bias[col];
#pragma unroll
      for (int r = 0; r < 4; ++r) {
        int row = bm + wr + i * 16 + quad * 4 + r;
        float v = (acc[i][j][r] + bv) * oscale;
        if (OF) {
          ((float*)out0)[(size_t)row * Ntot + col] = v;
        } else if (col < N0) {
          ((u16*)out0)[(size_t)row * N0 + col] = f2b(v);
        } else {
          ((u16*)out1)[(size_t)row * N1 + (col - N0)] = f2b(v);
        }
      }
    }
}

// ---------------------------------------------------------------------------
// Legacy GEMM: out[M,N] = (X[M,K] @ W[N,K]^T + bias[N]) * oscale
// XF/WF: 1 = fp32 source (convert at LDS store), 0 = bf16. OF: 1 = fp32 out.
// 64x128 tile, waves 1x4, register prefetch. kvn (N=576) + fallback paths.
// ---------------------------------------------------------------------------
template <int XF, int WF, int OF>
__global__ __launch_bounds__(256, 3) void gemm_kernel(
    const void* __restrict__ X, int lda, const void* __restrict__ W,
    const float* __restrict__ bias, void* __restrict__ out,
    int M, int N, int K, float oscale) {
  constexpr int LDT = 72;
  __shared__ alignas(16) u16 As[64 * LDT];
  __shared__ alignas(16) u16 Bs[128 * LDT];
  const int tid = threadIdx.x;
  const int wave = tid >> 6, lane = tid & 63;
  const int quad = lane >> 4, l16 = lane & 15;
  const int bm = blockIdx.x * 64, bn = blockIdx.y * 128;
  const int wn = wave * 32;
  const int srow = tid >> 3;           // 0..31
  const int scol = (tid & 7) * 8;      // 0..56

  f32x4 acc[4][2] = {};

  float4 pa32[2][2], pb32[4][2];
  uint4  pa16[2],    pb16[4];

  auto load_tile = [&](int k0) {
#pragma unroll
    for (int p = 0; p < 2; ++p) {
      size_t off = (size_t)(bm + srow + p * 32) * lda + k0 + scol;
      if (XF) {
        const float* s = (const float*)X + off;
        pa32[p][0] = *(const float4*)s;
        pa32[p][1] = *(const float4*)(s + 4);
      } else {
        pa16[p] = *(const uint4*)((const u16*)X + off);
      }
    }
#pragma unroll
    for (int p = 0; p < 4; ++p) {
      int n = bn + srow + p * 32;
      size_t off = (size_t)n * K + k0 + scol;
      if (WF) {
        if (n < N) {
          const float* s = (const float*)W + off;
          pb32[p][0] = *(const float4*)s;
          pb32[p][1] = *(const float4*)(s + 4);
        } else {
          pb32[p][0] = make_float4(0.f, 0.f, 0.f, 0.f);
          pb32[p][1] = make_float4(0.f, 0.f, 0.f, 0.f);
        }
      } else {
        if (n < N) pb16[p] = *(const uint4*)((const u16*)W + off);
        else { pb16[p].x = pb16[p].y = pb16[p].z = pb16[p].w = 0u; }
      }
    }
  };

  load_tile(0);
  for (int k0 = 0; k0 < K; k0 += 64) {
    __syncthreads();  // previous iteration's LDS readers done
#pragma unroll
    for (int p = 0; p < 2; ++p) {
      uint4 v;
      if (XF) v = pack8(pa32[p][0], pa32[p][1]); else v = pa16[p];
      *(uint4*)(&As[(srow + p * 32) * LDT + scol]) = v;
    }
#pragma unroll
    for (int p = 0; p < 4; ++p) {
      uint4 v;
      if (WF) v = pack8(pb32[p][0], pb32[p][1]); else v = pb16[p];
      *(uint4*)(&Bs[(srow + p * 32) * LDT + scol]) = v;
    }
    __syncthreads();  // also the compiler fence for the u16->bf16x8 pun
    if (k0 + 64 < K) load_tile(k0 + 64);  // latency hidden by MFMA below

#pragma unroll
    for (int kk = 0; kk < 64; kk += 32) {
      bf16x8 a[4], b[2];
#pragma unroll
      for (int i = 0; i < 4; ++i)
        a[i] = *(const bf16x8*)(&As[(i * 16 + l16) * LDT + kk + quad * 8]);
#pragma unroll
      for (int j = 0; j < 2; ++j)
        b[j] = *(const bf16x8*)(&Bs[(wn + j * 16 + l16) * LDT + kk + quad * 8]);
#pragma unroll
      for (int i = 0; i < 4; ++i)
#pragma unroll
        for (int j = 0; j < 2; ++j)
          acc[i][j] = __builtin_amdgcn_mfma_f32_16x16x32_bf16(a[i], b[j], acc[i][j], 0, 0, 0);
    }
  }

#pragma unroll
  for (int i = 0; i < 4; ++i)
#pragma unroll
    for (int j = 0; j < 2; ++j) {
      int col = bn + wn + j * 16 + l16;
      if (col < N) {
        float bv = bias[col];
#pragma unroll
        for (int r = 0; r < 4; ++r) {
          int row = bm + i * 16 + quad * 4 + r;
          float v = (acc[i][j][r] + bv) * oscale;
          if (OF) ((float*)out)[(size_t)row * N + col] = v;
          else    ((u16*)out)[(size_t)row * N + col] = f2b(v);
        }
      }
    }
}

// ---------------------------------------------------------------------------
__global__ void rmsnorm_kernel(u16* x, const float* __restrict__ w,
                               int C, int stride) {
  size_t base = (size_t)blockIdx.x * stride;
  float s = 0.f;
  for (int c = threadIdx.x; c < C; c += 256) { float v = b2f(x[base + c]); s += v * v; }
#pragma unroll
  for (int off = 32; off > 0; off >>= 1) s += __shfl_xor(s, off, 64);
  __shared__ float red[4];
  if ((threadIdx.x & 63) == 0) red[threadIdx.x >> 6] = s;
  __syncthreads();
  float tot = red[0] + red[1] + red[2] + red[3];
  float scale = rsqrtf(tot / (float)C + 1e-6f);
  for (int c = threadIdx.x; c < C; c += 256)
    x[base + c] = f2b(b2f(x[base + c]) * scale * w[c]);
}

// ---------------------------------------------------------------------------
__global__ void rope_kpe_kernel(const u16* __restrict__ kvn,
                                const float* __restrict__ fcos,
                                const float* __restrict__ fsin,
                                u16* __restrict__ kpe) {
  int idx = blockIdx.x * 256 + threadIdx.x;  // token*32 + i
  int t = idx >> 5, i = idx & 31;
  int s = t & (SEQ - 1);
  float c = fcos[s * 32 + i], sn = fsin[s * 32 + i];
  float xr = b2f(kvn[(size_t)t * 576 + 512 + 2 * i]);
  float xi = b2f(kvn[(size_t)t * 576 + 512 + 2 * i + 1]);
  kpe[(size_t)t * 64 + 2 * i]     = f2b(xr * c - xi * sn);
  kpe[(size_t)t * 64 + 2 * i + 1] = f2b(xr * sn + xi * c);
}

// ---------------------------------------------------------------------------
// In-place rope on q_pe, qb layout [4096 tokens, 8 heads x 192].
// ---------------------------------------------------------------------------
__global__ void rope_q_kernel(u16* q, const float* __restrict__ fcos,
                              const float* __restrict__ fsin) {
  int idx = blockIdx.x * 256 + threadIdx.x;  // t*256 + h*32 + i
  int t = idx >> 8, h = (idx >> 5) & 7, i = idx & 31;
  int s = t & (SEQ - 1);
  float c = fcos[s * 32 + i], sn = fsin[s * 32 + i];
  size_t base = (size_t)t * 1536 + h * 192 + 128 + 2 * i;
  float xr = b2f(q[base]), xi = b2f(q[base + 1]);
  q[base]     = f2b(xr * c - xi * sn);
  q[base + 1] = f2b(xr * sn + xi * c);
}

// ---------------------------------------------------------------------------
// Flash attention (causal).
// PAIRED=1 (merged path): grid (16,16,2) = 512 uniform blocks, each
// processes q-tiles {31-x, x} = exactly 33 K-tile iters; CU co-residents
// have EQUAL length -> sustained 2-residency (round-6 verified).
// PAIRED=0 (fallbacks): grid (32,8,2), complementary cross-batch mapping.
// r11: P-fence is compiler-only (Ps wave-private; keeps prefetch in flight).
// r12: V^T staging via cross-quad 4x4 u32 transpose + 8B stores (was 32
// scalar u16 stores/thread/iter -> 15.7M bank-conflict cycles/dispatch).
// ---------------------------------------------------------------------------
template <int PAIRED>
__global__ __launch_bounds__(256, 2) void attn_kernel(
    const u16* __restrict__ Q0,   // [4096, 1536] heads 0..7 (pre-scaled)
    const u16* __restrict__ Q1,   // [4096, 1536] heads 8..15
    const u16* __restrict__ KV0,  // [4096, 2048] heads 0..7 (k_nope|v)
    const u16* __restrict__ KV1,  // [4096, 2048] heads 8..15
    const u16* __restrict__ KPE,  // [4096, 64]
    u16* __restrict__ O,          // [4096, 2048]
    int hbase) {
  constexpr int LK = 200;
  constexpr int LP = 72;
  __shared__ alignas(16) u16 Ks[64 * LK];
  __shared__ alignas(16) u16 Ps[64 * LP];
  __shared__ alignas(16) u16 Vs[128 * LP];  // swizzled V^T

  const int tid = threadIdx.x;
  const int wave = tid >> 6, lane = tid & 63;
  const int quad = lane >> 4, l16 = lane & 15;
  const int h = hbase + blockIdx.y;       // global head 0..15
  const int hl = h & 7;
  const u16* __restrict__ Q   = (h & 8) ? Q1  : Q0;
  const u16* __restrict__ KVB = (h & 8) ? KV1 : KV0;
  const size_t tok0 = (size_t)blockIdx.z * SEQ;

  auto process = [&](int qt) {
    const int q0 = qt * 64;
    bf16x8 qf[6];
    {
      const u16* qp = Q + (tok0 + q0 + wave * 16 + l16) * 1536 + hl * 192 + quad * 8;
#pragma unroll
      for (int c = 0; c < 6; ++c) qf[c] = *(const bf16x8*)(qp + c * 32);
    }

    f32x4 o_acc[8] = {};
    float m_i[4], l_i[4];
#pragma unroll
    for (int r = 0; r < 4; ++r) { m_i[r] = NEGBIG; l_i[r] = 0.f; }

    const int nkt = qt + 1;
    uint4 kreg[6], vreg[4];
    auto load_tile = [&](int kt) {
      int k0 = kt * 64;
#pragma unroll
      for (int p = 0; p < 6; ++p) {
        int flat = tid + p * 256;
        int r = flat / 24, c8 = (flat % 24) * 8;
        const u16* src = (c8 < 128)
            ? (KVB + (tok0 + k0 + r) * 2048 + hl * 256 + c8)
            : (KPE + (tok0 + k0 + r) * 64 + (c8 - 128));
        kreg[p] = *(const uint4*)src;
      }
#pragma unroll
      for (int p = 0; p < 4; ++p) {
        int flat = tid + p * 256;
        int r = flat / 16, c8 = (flat % 16) * 8;
        vreg[p] = *(const uint4*)(KVB + (tok0 + k0 + r) * 2048 + hl * 256 + 128 + c8);
      }
    };

    load_tile(0);
    for (int kt = 0; kt < nkt; ++kt) {
      const int k0 = kt * 64;
      __syncthreads();  // B1: previous LDS readers done
#pragma unroll
      for (int p = 0; p < 6; ++p) {
        int flat = tid + p * 256;
        int r = flat / 24, c8 = (flat % 24) * 8;
        *(uint4*)(&Ks[r * LK + c8]) = kreg[p];
      }
      // r12: V^T staging. For issue p, quad-siblings {l16, l16+16, l16+32,
      // l16+48} hold rows r0..r0+3 (r0 = wave*4 + p*16) at the same cols
      // c8 = l16*8..+7. Two shfl_xor butterflies (16, 32) transpose the
      // 4x4 u32 block so this lane holds cols (c8+2*quad, +1) x rows
      // r0..r0+3. In the swizzled layout those 4 row-values per col are
      // contiguous (rs const over r0..r0+3, rl = rl0..rl0+3, rl0 in {0,4})
      // -> two 8B stores. Layout byte-identical to the old scalar stores.
#pragma unroll
      for (int p = 0; p < 4; ++p) {
        u32 w0 = vreg[p].x, w1 = vreg[p].y, w2 = vreg[p].z, w3 = vreg[p].w;
        // round 1: inner 2x2 transpose across quad bit0 (lane ^ 16)
        u32 a0 = __shfl_xor(w1, 16, 64), a1 = __shfl_xor(w0, 16, 64);
        u32 a2 = __shfl_xor(w3, 16, 64), a3 = __shfl_xor(w2, 16, 64);
        bool qb0 = (quad & 1) != 0;
        u32 r10 = qb0 ? a0 : w0, r11 = qb0 ? w1 : a1;
        u32 r12v = qb0 ? a2 : w2, r13 = qb0 ? w3 : a3;
        // round 2: outer 2x2 block transpose across quad bit1 (lane ^ 32)
        u32 b0 = __shfl_xor(r12v, 32, 64), b2 = __shfl_xor(r10, 32, 64);
        u32 b1 = __shfl_xor(r13, 32, 64), b3 = __shfl_xor(r11, 32, 64);
        bool qb1 = (quad & 2) != 0;
        u32 o0 = qb1 ? b0 : r10, o1 = qb1 ? b1 : r11;
        u32 o2 = qb1 ? r12v : b2, o3 = qb1 ? r13 : b3;
        // o[j] = sibling j's word[quad] = V[r0+j][c8+2q .. c8+2q+1]
        int r0 = wave * 4 + p * 16;
        int sw = ((r0 >> 3) ^ (l16 & 7)) << 3;
        int rl0 = r0 & 7;            // in {0,4}: 8B-aligned
        int nA = l16 * 8 + 2 * quad;
        u32 lo01 = (o0 & 0xffffu) | (o1 << 16);
        u32 lo23 = (o2 & 0xffffu) | (o3 << 16);
        u32 hi01 = (o0 >> 16) | (o1 & 0xffff0000u);
        u32 hi23 = (o2 >> 16) | (o3 & 0xffff0000u);
        *(uint2*)(&Vs[(size_t)nA * LP + sw + rl0])       = make_uint2(lo01, lo23);
        *(uint2*)(&Vs[(size_t)(nA + 1) * LP + sw + rl0]) = make_uint2(hi01, hi23);
      }
      __syncthreads();  // B2: Ks/Vs published to all waves
      if (kt + 1 < nkt) load_tile(kt + 1);

      f32x4 sc[4];
#pragma unroll
      for (int ni = 0; ni < 4; ++ni) {
        f32x4 a = {};
#pragma unroll
        for (int c = 0; c < 6; ++c) {
          bf16x8 kf = *(const bf16x8*)(&Ks[(ni * 16 + l16) * LK + c * 32 + quad * 8]);
          a = __builtin_amdgcn_mfma_f32_16x16x32_bf16(qf[c], kf, a, 0, 0, 0);
        }
        sc[ni] = a;
      }

      const int qrow_base = q0 + wave * 16 + quad * 4;
      if (kt == nkt - 1) {  // only the diagonal tile needs the causal mask
#pragma unroll
        for (int ni = 0; ni < 4; ++ni) {
          int col = k0 + ni * 16 + l16;
#pragma unroll
          for (int r = 0; r < 4; ++r)
            if (col > qrow_base + r) sc[ni][r] = NEGBIG;
        }
      }

      float mloc[4];
#pragma unroll
      for (int r = 0; r < 4; ++r) mloc[r] = NEGBIG;
#pragma unroll
      for (int ni = 0; ni < 4; ++ni)
#pragma unroll
        for (int r = 0; r < 4; ++r) mloc[r] = fmaxf(mloc[r], sc[ni][r]);
#pragma unroll
      for (int off = 1; off < 16; off <<= 1)
#pragma unroll
        for (int r = 0; r < 4; ++r) mloc[r] = fmaxf(mloc[r], __shfl_xor(mloc[r], off, 64));

      float alpha[4], rsum[4];
#pragma unroll
      for (int r = 0; r < 4; ++r) {
        float mn = fmaxf(m_i[r], mloc[r]);
        alpha[r] = __expf(m_i[r] - mn);
        m_i[r] = mn;
        rsum[r] = 0.f;
      }
#pragma unroll
      for (int ni = 0; ni < 4; ++ni)
#pragma unroll
        for (int r = 0; r < 4; ++r) {
          float p = __expf(sc[ni][r] - m_i[r]);
          sc[ni][r] = p;
          rsum[r] += p;
        }
#pragma unroll
      for (int off = 1; off < 16; off <<= 1)
#pragma unroll
        for (int r = 0; r < 4; ++r) rsum[r] += __shfl_xor(rsum[r], off, 64);
#pragma unroll
      for (int r = 0; r < 4; ++r) l_i[r] = l_i[r] * alpha[r] + rsum[r];

#pragma unroll
      for (int ni = 0; ni < 4; ++ni)
#pragma unroll
        for (int r = 0; r < 4; ++r)
          Ps[(wave * 16 + quad * 4 + r) * LP + ni * 16 + l16] = f2b(sc[ni][r]);

      // Ps rows [wave*16, wave*16+16) are written and read by the SAME wave
      // only; HW DS ops are in-order per wave, so a compiler fence suffices
      // (and keeps the load_tile(kt+1) prefetch in flight through PV).
      asm volatile("" ::: "memory");

#pragma unroll
      for (int t8 = 0; t8 < 8; ++t8)
#pragma unroll
        for (int r = 0; r < 4; ++r) o_acc[t8][r] *= alpha[r];

      bf16x8 pf0 = *(const bf16x8*)(&Ps[(wave * 16 + l16) * LP + quad * 8]);
      bf16x8 pf1 = *(const bf16x8*)(&Ps[(wave * 16 + l16) * LP + 32 + quad * 8]);
#pragma unroll
      for (int ni = 0; ni < 8; ++ni) {
        int n0 = ni * 16 + l16;
        int sw = (n0 >> 3) & 7;
        bf16x8 vf0 = *(const bf16x8*)(&Vs[n0 * LP + ((quad ^ sw) << 3)]);
        bf16x8 vf1 = *(const bf16x8*)(&Vs[n0 * LP + (((4 + quad) ^ sw) << 3)]);
        o_acc[ni] = __builtin_amdgcn_mfma_f32_16x16x32_bf16(pf0, vf0, o_acc[ni], 0, 0, 0);
        o_acc[ni] = __builtin_amdgcn_mfma_f32_16x16x32_bf16(pf1, vf1, o_acc[ni], 0, 0, 0);
      }
    }

#pragma unroll
    for (int ni = 0; ni < 8; ++ni) {
      int col = h * 128 + ni * 16 + l16;
#pragma unroll
      for (int r = 0; r < 4; ++r) {
        size_t row = tok0 + q0 + wave * 16 + quad * 4 + r;
        O[row * 2048 + col] = f2b(o_acc[ni][r] / l_i[r]);
      }
    }
  };

  if (PAIRED) {
    // Uniform 33 iters/block: long tile then short tile (round-6 verified).
    process(31 - (int)blockIdx.x);  // qt in [16,31]: 17..32 iters
    process((int)blockIdx.x);       // qt in [0,15]:  1..16 iters
  } else {
    // Complementary cross-batch pairing (round-2/4 verified).
    process(blockIdx.z == 0 ? (31 - (int)blockIdx.x) : (int)blockIdx.x);
  }
}

// ---------------------------------------------------------------------------
extern "C" void kernel_launch(void* const* d_in, const int* in_sizes, int n_in,
                              void* d_out, int out_size, void* d_ws, size_t ws_size,
                              hipStream_t stream) {
  const float* x      = (const float*)d_in[0];
  const float* fcos   = (const float*)d_in[1];
  const float* fsin   = (const float*)d_in[2];
  const float* wqa    = (const float*)d_in[3];
  const float* wqa_b  = (const float*)d_in[4];
  const float* qnw    = (const float*)d_in[5];
  const float* wqb    = (const float*)d_in[6];
  const float* wqb_b  = (const float*)d_in[7];
  const float* wkva   = (const float*)d_in[8];
  const float* wkva_b = (const float*)d_in[9];
  const float* kvnw   = (const float*)d_in[10];
  const float* wkvb   = (const float*)d_in[11];
  const float* wkvb_b = (const float*)d_in[12];
  const float* wo     = (const float*)d_in[13];
  const float* wo_b   = (const float*)d_in[14];

  char* ws = (char*)d_ws;
  u16* qn   = (u16*)(ws + 0);           // [4096,1536]
  u16* kvn  = (u16*)(ws + 12582912);    // [4096,576]
  u16* kpe  = (u16*)(ws + 17301504);    // [4096,64]
  u16* qbA  = (u16*)(ws + 17825792);    // [4096,1536] heads 0..7
  u16* kvB  = (u16*)(ws + 30408704);    // [4096,2048] heads 8..15
  u16* ao   = (u16*)(ws + 47185920);    // [4096,2048]

  dim3 blk(256);

  if (ws_size >= 123994112u) {
    // ---- merged path: r7 gemm_lds + sibling-merged dispatches; paired attn.
    u16* xb    = (u16*)(ws + 63963136);   // [4096,2048] bf16 x; later kvA
    u16* kvA   = (u16*)(ws + 63963136);   // heads 0..7 (reuses xb slot)
    u16* wqab  = (u16*)(ws + 80740352);   // [1536,2048]
    u16* wkvab = (u16*)(ws + 87031808);   // [576,2048]
    u16* wqbb  = (u16*)(ws + 89391104);   // [2*1536,1536]
    u16* wkvbw = (u16*)(ws + 98828288);   // [2*2048,512]
    u16* wob   = (u16*)(ws + 103022592);  // [2048,2048]
    u16* qbB   = (u16*)(ws + 111411200);  // [4096,1536] heads 8..15

    cvt_kernel<<<2048, blk, 0, stream>>>(x,    xb,    1048576);
    cvt_kernel<<<1536, blk, 0, stream>>>(wqa,  wqab,   393216);
    cvt_kernel<<< 576, blk, 0, stream>>>(wkva, wkvab,  147456);
    cvt_kernel<<<2048, blk, 0, stream>>>(wqb,  wqbb,   589824);
    cvt_kernel<<<1024, blk, 0, stream>>>(wkvb, wkvbw,  262144);
    cvt_kernel<<<2048, blk, 0, stream>>>(wo,   wob,    524288);

    gemm_lds_kernel<0><<<dim3(32, 12), blk, 0, stream>>>(xb, 2048, wqab, wqa_b, qn, qn, 1536, 1536, 2048, 1.0f);
    gemm_kernel<0,0,0><<<dim3(64, 5),  blk, 0, stream>>>(xb, 2048, wkvab, wkva_b, kvn, 4096, 576, 2048, 1.0f);
    rmsnorm_kernel<<<4096, blk, 0, stream>>>(qn, qnw, 1536, 1536);
    rmsnorm_kernel<<<4096, blk, 0, stream>>>(kvn, kvnw, 512, 576);
    rope_kpe_kernel<<<512, blk, 0, stream>>>(kvn, fcos, fsin, kpe);

    // q projection: BOTH head groups in one 768-block dispatch
    gemm_lds_kernel<0><<<dim3(32, 24), blk, 0, stream>>>(qn, 1536, wqbb, wqb_b, qbA, qbB, 1536, 3072, 1536, SCALE);
    rope_q_kernel<<<4096, blk, 0, stream>>>(qbA, fcos, fsin);
    rope_q_kernel<<<4096, blk, 0, stream>>>(qbB, fcos, fsin);
    // kv projection: BOTH groups in one 1024-block dispatch (split at 2048)
    gemm_lds_kernel<0><<<dim3(32, 32), blk, 0, stream>>>(kvn, 576, wkvbw, wkvb_b, kvA, kvB, 2048, 4096, 512, 1.0f);

    // one attn dispatch: 512 uniform 33-iter blocks, 2 equal/CU throughout
    attn_kernel<1><<<dim3(16, 16, 2), blk, 0, stream>>>(qbA, qbB, kvA, kvB, kpe, ao, 0);

    gemm_lds_kernel<1><<<dim3(32, 16), blk, 0, stream>>>(ao, 2048, wob, wo_b, (float*)d_out, (float*)d_out, 2048, 2048, 2048, 1.0f);
  } else if (ws_size >= 111411200u) {
    // ---- round-4 path: bf16 weights, per-group attn (verified 635 us).
    u16* xb    = (u16*)(ws + 63963136);
    u16* wqab  = (u16*)(ws + 80740352);
    u16* wkvab = (u16*)(ws + 87031808);
    u16* wqbb  = (u16*)(ws + 89391104);
    u16* wkvbw = (u16*)(ws + 98828288);
    u16* wob   = (u16*)(ws + 103022592);

    cvt_kernel<<<2048, blk, 0, stream>>>(x,    xb,    1048576);
    cvt_kernel<<<1536, blk, 0, stream>>>(wqa,  wqab,   393216);
    cvt_kernel<<< 576, blk, 0, stream>>>(wkva, wkvab,  147456);
    cvt_kernel<<<2048, blk, 0, stream>>>(wqb,  wqbb,   589824);
    cvt_kernel<<<1024, blk, 0, stream>>>(wkvb, wkvbw,  262144);
    cvt_kernel<<<2048, blk, 0, stream>>>(wo,   wob,    524288);

    gemm_kernel<0,0,0><<<dim3(64, 12), blk, 0, stream>>>(xb, 2048, wqab, wqa_b, qn, 4096, 1536, 2048, 1.0f);
    gemm_kernel<0,0,0><<<dim3(64, 5),  blk, 0, stream>>>(xb, 2048, wkvab, wkva_b, kvn, 4096, 576, 2048, 1.0f);
    rmsnorm_kernel<<<4096, blk, 0, stream>>>(qn, qnw, 1536, 1536);
    rmsnorm_kernel<<<4096, blk, 0, stream>>>(kvn, kvnw, 512, 576);
    rope_kpe_kernel<<<512, blk, 0, stream>>>(kvn, fcos, fsin, kpe);

    for (int g = 0; g < 2; ++g) {
      const u16* wqb_g   = wqbb + (size_t)g * 1536 * 1536;
      const float* wqb_bg  = wqb_b + g * 1536;
      const u16* wkvb_g  = wkvbw + (size_t)g * 2048 * 512;
      const float* wkvb_bg = wkvb_b + g * 2048;
      gemm_kernel<0,0,0><<<dim3(64, 12), blk, 0, stream>>>(qn, 1536, wqb_g, wqb_bg, qbA, 4096, 1536, 1536, SCALE);
      rope_q_kernel<<<4096, blk, 0, stream>>>(qbA, fcos, fsin);
      gemm_kernel<0,0,0><<<dim3(64, 16), blk, 0, stream>>>(kvn, 576, wkvb_g, wkvb_bg, kvB, 4096, 2048, 512, 1.0f);
      attn_kernel<0><<<dim3(32, 8, 2), blk, 0, stream>>>(qbA, qbA, kvB, kvB, kpe, ao, g * 8);
    }

    gemm_kernel<0,0,1><<<dim3(64, 16), blk, 0, stream>>>(ao, 2048, wob, wo_b, (float*)d_out, 4096, 2048, 2048, 1.0f);
  } else {
    // ---- legacy path: fp32 weights converted in-loop (round-2).
    gemm_kernel<1,1,0><<<dim3(64, 12), blk, 0, stream>>>(x, 2048, wqa, wqa_b, qn, 4096, 1536, 2048, 1.0f);
    gemm_kernel<1,1,0><<<dim3(64, 5),  blk, 0, stream>>>(x, 2048, wkva, wkva_b, kvn, 4096, 576, 2048, 1.0f);
    rmsnorm_kernel<<<4096, blk, 0, stream>>>(qn, qnw, 1536, 1536);
    rmsnorm_kernel<<<4096, blk, 0, stream>>>(kvn, kvnw, 512, 576);
    rope_kpe_kernel<<<512, blk, 0, stream>>>(kvn, fcos, fsin, kpe);

    for (int g = 0; g < 2; ++g) {
      const float* wqb_g   = wqb + (size_t)g * 1536 * 1536;
      const float* wqb_bg  = wqb_b + g * 1536;
      const float* wkvb_g  = wkvb + (size_t)g * 2048 * 512;
      const float* wkvb_bg = wkvb_b + g * 2048;
      gemm_kernel<0,1,0><<<dim3(64, 12), blk, 0, stream>>>(qn, 1536, wqb_g, wqb_bg, qbA, 4096, 1536, 1536, SCALE);
      rope_q_kernel<<<4096, blk, 0, stream>>>(qbA, fcos, fsin);
      gemm_kernel<0,1,0><<<dim3(64, 16), blk, 0, stream>>>(kvn, 576, wkvb_g, wkvb_bg, kvB, 4096, 2048, 512, 1.0f);
      attn_kernel<0><<<dim3(32, 8, 2), blk, 0, stream>>>(qbA, qbA, kvB, kvB, kpe, ao, g * 8);
    }

    gemm_kernel<0,1,1><<<dim3(64, 16), blk, 0, stream>>>(ao, 2048, wo, wo_b, (float*)d_out, 4096, 2048, 2048, 1.0f);
  }
}

// Round 13
// 537.214 us; speedup vs baseline: 1.0483x; 1.0483x over previous
//
#include <hip/hip_runtime.h>

// MLA prefill: B=2, S=2048, DIM=2048, NH=16, Q_LORA=1536, KV_LORA=512,
// NOPE=128, ROPE=64, VHD=128, QK_HD=192.
// I/O dtype: FP32. Internal: bf16 MFMA.
//
// Round-13: r12's register-transpose V-staging REVERTED (conflicts only
// fell 15.7M->13.5M — scalar V-stores were ~2.2M of the total, and the
// shfl/cndmask VALU cost exceeded the saving; attn 183->208). Back to
// r11's exact attn (539.1us best) + ONE new lever: s_setprio(1) around
// the QK and PV MFMA clusters. The two co-resident blocks per CU run
// independent phases, so the MFMA-issuing block's waves get priority
// over the other block's staging loads (T5; +4-7% on attn with
// independent-phase waves, ~0 when lockstep).
//
// WS plan (merged path, high-water 123,994,112 B):
//   qn    @ 0           [4096,1536]
//   kvn   @ 12,582,912  [4096, 576]  (cols 512..575 raw pe)
//   kpe   @ 17,301,504  [4096,  64]
//   qbA   @ 17,825,792  [4096,1536]  heads 0..7, pre-scaled by SCALE
//   kvB   @ 30,408,704  [4096,2048]  heads 8..15 (k_nope128|v128)
//   ao    @ 47,185,920  [4096,2048]
//   xb    @ 63,963,136  [4096,2048]  bf16 of x;  kvA reuses this slot
//   wqab  @ 80,740,352  [1536,2048]  bf16 weights
//   wkvab @ 87,031,808  [576,2048]
//   wqbb  @ 89,391,104  [2*1536,1536]
//   wkvbw @ 98,828,288  [2*2048,512]
//   wob   @103,022,592  [2048,2048]
//   qbB   @111,411,200  [4096,1536]  heads 8..15
// Fallbacks: ws>=111,411,200 -> round-4 path; else round-2 legacy path.

typedef __bf16 bf16x8 __attribute__((ext_vector_type(8)));
typedef float f32x4 __attribute__((ext_vector_type(4)));
typedef unsigned short u16;

#define SEQ 2048
#define SCALE 0.07216878364870323f  // 192^-0.5
#define NEGBIG -30000.0f            // expf underflows to exactly 0

__device__ __forceinline__ float b2f(u16 u) {
  union { unsigned u; float f; } c; c.u = ((unsigned)u) << 16; return c.f;
}
__device__ __forceinline__ u16 f2b(float f) {  // RNE fp32->bf16
  union { float f; unsigned u; } c; c.f = f;
  unsigned r = (c.u + 0x7fffu + ((c.u >> 16) & 1u)) >> 16;
  return (u16)r;
}
__device__ __forceinline__ uint4 pack8(float4 a, float4 b) {
  union { uint4 v; u16 e[8]; } t;
  t.e[0] = f2b(a.x); t.e[1] = f2b(a.y); t.e[2] = f2b(a.z); t.e[3] = f2b(a.w);
  t.e[4] = f2b(b.x); t.e[5] = f2b(b.y); t.e[6] = f2b(b.z); t.e[7] = f2b(b.w);
  return t.v;
}

// async 16B global -> LDS (HW writes lane's 16B to ldsbase + lane*16)
#define GLOAD_LDS16(gsrc, ldst)                                              \
  __builtin_amdgcn_global_load_lds(                                          \
      (const __attribute__((address_space(1))) unsigned int*)(gsrc),         \
      (__attribute__((address_space(3))) unsigned int*)(ldst), 16, 0, 0)

// ---------------------------------------------------------------------------
// fp32 -> bf16 bulk convert (n8 = element_count / 8)
// ---------------------------------------------------------------------------
__global__ void cvt_kernel(const float* __restrict__ src, u16* __restrict__ dst,
                           long n8) {
  long i = (long)blockIdx.x * 256 + threadIdx.x;
  long stride = (long)gridDim.x * 256;
  for (; i < n8; i += stride) {
    const float4* s = (const float4*)(src + i * 8);
    float4 a = s[0], b = s[1];
    *(uint4*)(dst + i * 8) = pack8(a, b);
  }
}

// ---------------------------------------------------------------------------
// gemm_lds (r7-verified structure): out[4096,Ntot] = X @ W^T + bias, split
// across two destination buffers at col N0 (out0 cols [0,N0), stride N0;
// out1 cols [N0,Ntot), stride Ntot-N0). Requires N%128==0, K%64==0.
// 128x128 tile, BK=64, 4 waves 2x2 (acc 4x4), double-buffered
// global_load_lds staging, ONE barrier per K-step.
// LDS: XOR-swizzled LDS[r][c ^ ((r&7)*8)] = M[r][k0+c] via linear
// gload_lds dest + pre-swizzled global source col ((lane&7)^(lane>>3))*8;
// fragment ds_read applies the same XOR (identity round-trip).
// ---------------------------------------------------------------------------
template <int OF>
__global__ __launch_bounds__(256) void gemm_lds_kernel(
    const u16* __restrict__ X, int lda, const u16* __restrict__ W,
    const float* __restrict__ bias, void* __restrict__ out0,
    void* __restrict__ out1, int N0, int Ntot, int K, float oscale) {
  __shared__ alignas(16) u16 As[2][128 * 64];
  __shared__ alignas(16) u16 Bs[2][128 * 64];
  const int tid = threadIdx.x;
  const int wave = tid >> 6, lane = tid & 63;
  const int quad = lane >> 4, l16 = lane & 15;
  const int wr = (wave >> 1) * 64, wc = (wave & 1) * 64;
  const int bm = blockIdx.x * 128, bn = blockIdx.y * 128;
  const int srow0 = wave * 32 + (lane >> 3);          // + p*8
  const int gcol = ((lane & 7) ^ (lane >> 3)) * 8;    // pre-swizzled source col

  f32x4 acc[4][4] = {};

  auto stage = [&](int buf, int k0) {
#pragma unroll
    for (int p = 0; p < 4; ++p) {
      int row = srow0 + p * 8;
      const u16* ga = X + (size_t)(bm + row) * lda + k0 + gcol;
      const u16* gb = W + (size_t)(bn + row) * K + k0 + gcol;
      char* la = (char*)(&As[buf][0]) + (wave * 4 + p) * 1024;
      char* lb = (char*)(&Bs[buf][0]) + (wave * 4 + p) * 1024;
      GLOAD_LDS16(ga, la);
      GLOAD_LDS16(gb, lb);
    }
  };

  const int nk = K >> 6;
  stage(0, 0);
  int cur = 0;
  for (int kt = 0; kt < nk; ++kt) {
    __syncthreads();  // vmcnt drain: buf[cur] staged; prev readers of buf[cur^1] done
    if (kt + 1 < nk) stage(cur ^ 1, (kt + 1) * 64);  // flies under MFMA below
    const u16* as = &As[cur][0];
    const u16* bs = &Bs[cur][0];
#pragma unroll
    for (int kk = 0; kk < 64; kk += 32) {
      const int cs = (kk + quad * 8) ^ ((l16 & 7) * 8);
      bf16x8 a[4], b[4];
#pragma unroll
      for (int i = 0; i < 4; ++i)
        a[i] = *(const bf16x8*)(as + (wr + i * 16 + l16) * 64 + cs);
#pragma unroll
      for (int j = 0; j < 4; ++j)
        b[j] = *(const bf16x8*)(bs + (wc + j * 16 + l16) * 64 + cs);
#pragma unroll
      for (int i = 0; i < 4; ++i)
#pragma unroll
        for (int j = 0; j < 4; ++j)
          acc[i][j] = __builtin_amdgcn_mfma_f32_16x16x32_bf16(a[i], b[j], acc[i][j], 0, 0, 0);
    }
    cur ^= 1;
  }

  const int N1 = Ntot - N0;
#pragma unroll
  for (int i = 0; i < 4; ++i)
#pragma unroll
    for (int j = 0; j < 4; ++j) {
      int col = bn + wc + j * 16 + l16;
      float bv = bias[col];
#pragma unroll
      for (int r = 0; r < 4; ++r) {
        int row = bm + wr + i * 16 + quad * 4 + r;
        float v = (acc[i][j][r] + bv) * oscale;
        if (OF) {
          ((float*)out0)[(size_t)row * Ntot + col] = v;
        } else if (col < N0) {
          ((u16*)out0)[(size_t)row * N0 + col] = f2b(v);
        } else {
          ((u16*)out1)[(size_t)row * N1 + (col - N0)] = f2b(v);
        }
      }
    }
}

// ---------------------------------------------------------------------------
// Legacy GEMM: out[M,N] = (X[M,K] @ W[N,K]^T + bias[N]) * oscale
// XF/WF: 1 = fp32 source (convert at LDS store), 0 = bf16. OF: 1 = fp32 out.
// 64x128 tile, waves 1x4, register prefetch. kvn (N=576) + fallback paths.
// ---------------------------------------------------------------------------
template <int XF, int WF, int OF>
__global__ __launch_bounds__(256, 3) void gemm_kernel(
    const void* __restrict__ X, int lda, const void* __restrict__ W,
    const float* __restrict__ bias, void* __restrict__ out,
    int M, int N, int K, float oscale) {
  constexpr int LDT = 72;
  __shared__ alignas(16) u16 As[64 * LDT];
  __shared__ alignas(16) u16 Bs[128 * LDT];
  const int tid = threadIdx.x;
  const int wave = tid >> 6, lane = tid & 63;
  const int quad = lane >> 4, l16 = lane & 15;
  const int bm = blockIdx.x * 64, bn = blockIdx.y * 128;
  const int wn = wave * 32;
  const int srow = tid >> 3;           // 0..31
  const int scol = (tid & 7) * 8;      // 0..56

  f32x4 acc[4][2] = {};

  float4 pa32[2][2], pb32[4][2];
  uint4  pa16[2],    pb16[4];

  auto load_tile = [&](int k0) {
#pragma unroll
    for (int p = 0; p < 2; ++p) {
      size_t off = (size_t)(bm + srow + p * 32) * lda + k0 + scol;
      if (XF) {
        const float* s = (const float*)X + off;
        pa32[p][0] = *(const float4*)s;
        pa32[p][1] = *(const float4*)(s + 4);
      } else {
        pa16[p] = *(const uint4*)((const u16*)X + off);
      }
    }
#pragma unroll
    for (int p = 0; p < 4; ++p) {
      int n = bn + srow + p * 32;
      size_t off = (size_t)n * K + k0 + scol;
      if (WF) {
        if (n < N) {
          const float* s = (const float*)W + off;
          pb32[p][0] = *(const float4*)s;
          pb32[p][1] = *(const float4*)(s + 4);
        } else {
          pb32[p][0] = make_float4(0.f, 0.f, 0.f, 0.f);
          pb32[p][1] = make_float4(0.f, 0.f, 0.f, 0.f);
        }
      } else {
        if (n < N) pb16[p] = *(const uint4*)((const u16*)W + off);
        else { pb16[p].x = pb16[p].y = pb16[p].z = pb16[p].w = 0u; }
      }
    }
  };

  load_tile(0);
  for (int k0 = 0; k0 < K; k0 += 64) {
    __syncthreads();  // previous iteration's LDS readers done
#pragma unroll
    for (int p = 0; p < 2; ++p) {
      uint4 v;
      if (XF) v = pack8(pa32[p][0], pa32[p][1]); else v = pa16[p];
      *(uint4*)(&As[(srow + p * 32) * LDT + scol]) = v;
    }
#pragma unroll
    for (int p = 0; p < 4; ++p) {
      uint4 v;
      if (WF) v = pack8(pb32[p][0], pb32[p][1]); else v = pb16[p];
      *(uint4*)(&Bs[(srow + p * 32) * LDT + scol]) = v;
    }
    __syncthreads();  // also the compiler fence for the u16->bf16x8 pun
    if (k0 + 64 < K) load_tile(k0 + 64);  // latency hidden by MFMA below

#pragma unroll
    for (int kk = 0; kk < 64; kk += 32) {
      bf16x8 a[4], b[2];
#pragma unroll
      for (int i = 0; i < 4; ++i)
        a[i] = *(const bf16x8*)(&As[(i * 16 + l16) * LDT + kk + quad * 8]);
#pragma unroll
      for (int j = 0; j < 2; ++j)
        b[j] = *(const bf16x8*)(&Bs[(wn + j * 16 + l16) * LDT + kk + quad * 8]);
#pragma unroll
      for (int i = 0; i < 4; ++i)
#pragma unroll
        for (int j = 0; j < 2; ++j)
          acc[i][j] = __builtin_amdgcn_mfma_f32_16x16x32_bf16(a[i], b[j], acc[i][j], 0, 0, 0);
    }
  }

#pragma unroll
  for (int i = 0; i < 4; ++i)
#pragma unroll
    for (int j = 0; j < 2; ++j) {
      int col = bn + wn + j * 16 + l16;
      if (col < N) {
        float bv = bias[col];
#pragma unroll
        for (int r = 0; r < 4; ++r) {
          int row = bm + i * 16 + quad * 4 + r;
          float v = (acc[i][j][r] + bv) * oscale;
          if (OF) ((float*)out)[(size_t)row * N + col] = v;
          else    ((u16*)out)[(size_t)row * N + col] = f2b(v);
        }
      }
    }
}

// ---------------------------------------------------------------------------
__global__ void rmsnorm_kernel(u16* x, const float* __restrict__ w,
                               int C, int stride) {
  size_t base = (size_t)blockIdx.x * stride;
  float s = 0.f;
  for (int c = threadIdx.x; c < C; c += 256) { float v = b2f(x[base + c]); s += v * v; }
#pragma unroll
  for (int off = 32; off > 0; off >>= 1) s += __shfl_xor(s, off, 64);
  __shared__ float red[4];
  if ((threadIdx.x & 63) == 0) red[threadIdx.x >> 6] = s;
  __syncthreads();
  float tot = red[0] + red[1] + red[2] + red[3];
  float scale = rsqrtf(tot / (float)C + 1e-6f);
  for (int c = threadIdx.x; c < C; c += 256)
    x[base + c] = f2b(b2f(x[base + c]) * scale * w[c]);
}

// ---------------------------------------------------------------------------
__global__ void rope_kpe_kernel(const u16* __restrict__ kvn,
                                const float* __restrict__ fcos,
                                const float* __restrict__ fsin,
                                u16* __restrict__ kpe) {
  int idx = blockIdx.x * 256 + threadIdx.x;  // token*32 + i
  int t = idx >> 5, i = idx & 31;
  int s = t & (SEQ - 1);
  float c = fcos[s * 32 + i], sn = fsin[s * 32 + i];
  float xr = b2f(kvn[(size_t)t * 576 + 512 + 2 * i]);
  float xi = b2f(kvn[(size_t)t * 576 + 512 + 2 * i + 1]);
  kpe[(size_t)t * 64 + 2 * i]     = f2b(xr * c - xi * sn);
  kpe[(size_t)t * 64 + 2 * i + 1] = f2b(xr * sn + xi * c);
}

// ---------------------------------------------------------------------------
// In-place rope on q_pe, qb layout [4096 tokens, 8 heads x 192].
// ---------------------------------------------------------------------------
__global__ void rope_q_kernel(u16* q, const float* __restrict__ fcos,
                              const float* __restrict__ fsin) {
  int idx = blockIdx.x * 256 + threadIdx.x;  // t*256 + h*32 + i
  int t = idx >> 8, h = (idx >> 5) & 7, i = idx & 31;
  int s = t & (SEQ - 1);
  float c = fcos[s * 32 + i], sn = fsin[s * 32 + i];
  size_t base = (size_t)t * 1536 + h * 192 + 128 + 2 * i;
  float xr = b2f(q[base]), xi = b2f(q[base + 1]);
  q[base]     = f2b(xr * c - xi * sn);
  q[base + 1] = f2b(xr * sn + xi * c);
}

// ---------------------------------------------------------------------------
// Flash attention (causal).
// PAIRED=1 (merged path): grid (16,16,2) = 512 uniform blocks, each
// processes q-tiles {31-x, x} = exactly 33 K-tile iters; CU co-residents
// have EQUAL length -> sustained 2-residency (round-6 verified).
// PAIRED=0 (fallbacks): grid (32,8,2), complementary cross-batch mapping.
// r11: P-fence is compiler-only (Ps wave-private; keeps prefetch in flight).
// r13: s_setprio(1) around QK and PV MFMA clusters — the two co-resident
// blocks per CU are at independent phases, so MFMA-issuing waves get
// scheduler priority over the other block's staging loads (T5).
// ---------------------------------------------------------------------------
template <int PAIRED>
__global__ __launch_bounds__(256, 2) void attn_kernel(
    const u16* __restrict__ Q0,   // [4096, 1536] heads 0..7 (pre-scaled)
    const u16* __restrict__ Q1,   // [4096, 1536] heads 8..15
    const u16* __restrict__ KV0,  // [4096, 2048] heads 0..7 (k_nope|v)
    const u16* __restrict__ KV1,  // [4096, 2048] heads 8..15
    const u16* __restrict__ KPE,  // [4096, 64]
    u16* __restrict__ O,          // [4096, 2048]
    int hbase) {
  constexpr int LK = 200;
  constexpr int LP = 72;
  __shared__ alignas(16) u16 Ks[64 * LK];
  __shared__ alignas(16) u16 Ps[64 * LP];
  __shared__ alignas(16) u16 Vs[128 * LP];  // swizzled V^T

  const int tid = threadIdx.x;
  const int wave = tid >> 6, lane = tid & 63;
  const int quad = lane >> 4, l16 = lane & 15;
  const int h = hbase + blockIdx.y;       // global head 0..15
  const int hl = h & 7;
  const u16* __restrict__ Q   = (h & 8) ? Q1  : Q0;
  const u16* __restrict__ KVB = (h & 8) ? KV1 : KV0;
  const size_t tok0 = (size_t)blockIdx.z * SEQ;

  auto process = [&](int qt) {
    const int q0 = qt * 64;
    bf16x8 qf[6];
    {
      const u16* qp = Q + (tok0 + q0 + wave * 16 + l16) * 1536 + hl * 192 + quad * 8;
#pragma unroll
      for (int c = 0; c < 6; ++c) qf[c] = *(const bf16x8*)(qp + c * 32);
    }

    f32x4 o_acc[8] = {};
    float m_i[4], l_i[4];
#pragma unroll
    for (int r = 0; r < 4; ++r) { m_i[r] = NEGBIG; l_i[r] = 0.f; }

    const int nkt = qt + 1;
    uint4 kreg[6], vreg[4];
    auto load_tile = [&](int kt) {
      int k0 = kt * 64;
#pragma unroll
      for (int p = 0; p < 6; ++p) {
        int flat = tid + p * 256;
        int r = flat / 24, c8 = (flat % 24) * 8;
        const u16* src = (c8 < 128)
            ? (KVB + (tok0 + k0 + r) * 2048 + hl * 256 + c8)
            : (KPE + (tok0 + k0 + r) * 64 + (c8 - 128));
        kreg[p] = *(const uint4*)src;
      }
#pragma unroll
      for (int p = 0; p < 4; ++p) {
        int flat = tid + p * 256;
        int r = flat / 16, c8 = (flat % 16) * 8;
        vreg[p] = *(const uint4*)(KVB + (tok0 + k0 + r) * 2048 + hl * 256 + 128 + c8);
      }
    };

    load_tile(0);
    for (int kt = 0; kt < nkt; ++kt) {
      const int k0 = kt * 64;
      __syncthreads();  // B1: previous LDS readers done
#pragma unroll
      for (int p = 0; p < 6; ++p) {
        int flat = tid + p * 256;
        int r = flat / 24, c8 = (flat % 24) * 8;
        *(uint4*)(&Ks[r * LK + c8]) = kreg[p];
      }
#pragma unroll
      for (int p = 0; p < 4; ++p) {
        int flat = tid + p * 256;
        int r = flat / 16, c8 = (flat % 16) * 8;
        union { uint4 v4; u16 e[8]; } t;
        t.v4 = vreg[p];
        int rs = r >> 3, rl = r & 7;
#pragma unroll
        for (int j = 0; j < 8; ++j) {
          int n = c8 + j;
          Vs[n * LP + ((rs ^ ((n >> 3) & 7)) << 3) + rl] = t.e[j];
        }
      }
      __syncthreads();  // B2: Ks/Vs published to all waves
      if (kt + 1 < nkt) load_tile(kt + 1);

      f32x4 sc[4];
      __builtin_amdgcn_s_setprio(1);  // r13: favor QK MFMA over co-resident block's staging
#pragma unroll
      for (int ni = 0; ni < 4; ++ni) {
        f32x4 a = {};
#pragma unroll
        for (int c = 0; c < 6; ++c) {
          bf16x8 kf = *(const bf16x8*)(&Ks[(ni * 16 + l16) * LK + c * 32 + quad * 8]);
          a = __builtin_amdgcn_mfma_f32_16x16x32_bf16(qf[c], kf, a, 0, 0, 0);
        }
        sc[ni] = a;
      }
      __builtin_amdgcn_s_setprio(0);

      const int qrow_base = q0 + wave * 16 + quad * 4;
      if (kt == nkt - 1) {  // only the diagonal tile needs the causal mask
#pragma unroll
        for (int ni = 0; ni < 4; ++ni) {
          int col = k0 + ni * 16 + l16;
#pragma unroll
          for (int r = 0; r < 4; ++r)
            if (col > qrow_base + r) sc[ni][r] = NEGBIG;
        }
      }

      float mloc[4];
#pragma unroll
      for (int r = 0; r < 4; ++r) mloc[r] = NEGBIG;
#pragma unroll
      for (int ni = 0; ni < 4; ++ni)
#pragma unroll
        for (int r = 0; r < 4; ++r) mloc[r] = fmaxf(mloc[r], sc[ni][r]);
#pragma unroll
      for (int off = 1; off < 16; off <<= 1)
#pragma unroll
        for (int r = 0; r < 4; ++r) mloc[r] = fmaxf(mloc[r], __shfl_xor(mloc[r], off, 64));

      float alpha[4], rsum[4];
#pragma unroll
      for (int r = 0; r < 4; ++r) {
        float mn = fmaxf(m_i[r], mloc[r]);
        alpha[r] = __expf(m_i[r] - mn);
        m_i[r] = mn;
        rsum[r] = 0.f;
      }
#pragma unroll
      for (int ni = 0; ni < 4; ++ni)
#pragma unroll
        for (int r = 0; r < 4; ++r) {
          float p = __expf(sc[ni][r] - m_i[r]);
          sc[ni][r] = p;
          rsum[r] += p;
        }
#pragma unroll
      for (int off = 1; off < 16; off <<= 1)
#pragma unroll
        for (int r = 0; r < 4; ++r) rsum[r] += __shfl_xor(rsum[r], off, 64);
#pragma unroll
      for (int r = 0; r < 4; ++r) l_i[r] = l_i[r] * alpha[r] + rsum[r];

#pragma unroll
      for (int ni = 0; ni < 4; ++ni)
#pragma unroll
        for (int r = 0; r < 4; ++r)
          Ps[(wave * 16 + quad * 4 + r) * LP + ni * 16 + l16] = f2b(sc[ni][r]);

      // Ps rows [wave*16, wave*16+16) are written and read by the SAME wave
      // only; HW DS ops are in-order per wave, so a compiler fence suffices
      // (and keeps the load_tile(kt+1) prefetch in flight through PV).
      asm volatile("" ::: "memory");

#pragma unroll
      for (int t8 = 0; t8 < 8; ++t8)
#pragma unroll
        for (int r = 0; r < 4; ++r) o_acc[t8][r] *= alpha[r];

      bf16x8 pf0 = *(const bf16x8*)(&Ps[(wave * 16 + l16) * LP + quad * 8]);
      bf16x8 pf1 = *(const bf16x8*)(&Ps[(wave * 16 + l16) * LP + 32 + quad * 8]);
      __builtin_amdgcn_s_setprio(1);  // r13: favor PV MFMA cluster
#pragma unroll
      for (int ni = 0; ni < 8; ++ni) {
        int n0 = ni * 16 + l16;
        int sw = (n0 >> 3) & 7;
        bf16x8 vf0 = *(const bf16x8*)(&Vs[n0 * LP + ((quad ^ sw) << 3)]);
        bf16x8 vf1 = *(const bf16x8*)(&Vs[n0 * LP + (((4 + quad) ^ sw) << 3)]);
        o_acc[ni] = __builtin_amdgcn_mfma_f32_16x16x32_bf16(pf0, vf0, o_acc[ni], 0, 0, 0);
        o_acc[ni] = __builtin_amdgcn_mfma_f32_16x16x32_bf16(pf1, vf1, o_acc[ni], 0, 0, 0);
      }
      __builtin_amdgcn_s_setprio(0);
    }

#pragma unroll
    for (int ni = 0; ni < 8; ++ni) {
      int col = h * 128 + ni * 16 + l16;
#pragma unroll
      for (int r = 0; r < 4; ++r) {
        size_t row = tok0 + q0 + wave * 16 + quad * 4 + r;
        O[row * 2048 + col] = f2b(o_acc[ni][r] / l_i[r]);
      }
    }
  };

  if (PAIRED) {
    // Uniform 33 iters/block: long tile then short tile (round-6 verified).
    process(31 - (int)blockIdx.x);  // qt in [16,31]: 17..32 iters
    process((int)blockIdx.x);       // qt in [0,15]:  1..16 iters
  } else {
    // Complementary cross-batch pairing (round-2/4 verified).
    process(blockIdx.z == 0 ? (31 - (int)blockIdx.x) : (int)blockIdx.x);
  }
}

// ---------------------------------------------------------------------------
extern "C" void kernel_launch(void* const* d_in, const int* in_sizes, int n_in,
                              void* d_out, int out_size, void* d_ws, size_t ws_size,
                              hipStream_t stream) {
  const float* x      = (const float*)d_in[0];
  const float* fcos   = (const float*)d_in[1];
  const float* fsin   = (const float*)d_in[2];
  const float* wqa    = (const float*)d_in[3];
  const float* wqa_b  = (const float*)d_in[4];
  const float* qnw    = (const float*)d_in[5];
  const float* wqb    = (const float*)d_in[6];
  const float* wqb_b  = (const float*)d_in[7];
  const float* wkva   = (const float*)d_in[8];
  const float* wkva_b = (const float*)d_in[9];
  const float* kvnw   = (const float*)d_in[10];
  const float* wkvb   = (const float*)d_in[11];
  const float* wkvb_b = (const float*)d_in[12];
  const float* wo     = (const float*)d_in[13];
  const float* wo_b   = (const float*)d_in[14];

  char* ws = (char*)d_ws;
  u16* qn   = (u16*)(ws + 0);           // [4096,1536]
  u16* kvn  = (u16*)(ws + 12582912);    // [4096,576]
  u16* kpe  = (u16*)(ws + 17301504);    // [4096,64]
  u16* qbA  = (u16*)(ws + 17825792);    // [4096,1536] heads 0..7
  u16* kvB  = (u16*)(ws + 30408704);    // [4096,2048] heads 8..15
  u16* ao   = (u16*)(ws + 47185920);    // [4096,2048]

  dim3 blk(256);

  if (ws_size >= 123994112u) {
    // ---- merged path: r7 gemm_lds + sibling-merged dispatches; paired attn.
    u16* xb    = (u16*)(ws + 63963136);   // [4096,2048] bf16 x; later kvA
    u16* kvA   = (u16*)(ws + 63963136);   // heads 0..7 (reuses xb slot)
    u16* wqab  = (u16*)(ws + 80740352);   // [1536,2048]
    u16* wkvab = (u16*)(ws + 87031808);   // [576,2048]
    u16* wqbb  = (u16*)(ws + 89391104);   // [2*1536,1536]
    u16* wkvbw = (u16*)(ws + 98828288);   // [2*2048,512]
    u16* wob   = (u16*)(ws + 103022592);  // [2048,2048]
    u16* qbB   = (u16*)(ws + 111411200);  // [4096,1536] heads 8..15

    cvt_kernel<<<2048, blk, 0, stream>>>(x,    xb,    1048576);
    cvt_kernel<<<1536, blk, 0, stream>>>(wqa,  wqab,   393216);
    cvt_kernel<<< 576, blk, 0, stream>>>(wkva, wkvab,  147456);
    cvt_kernel<<<2048, blk, 0, stream>>>(wqb,  wqbb,   589824);
    cvt_kernel<<<1024, blk, 0, stream>>>(wkvb, wkvbw,  262144);
    cvt_kernel<<<2048, blk, 0, stream>>>(wo,   wob,    524288);

    gemm_lds_kernel<0><<<dim3(32, 12), blk, 0, stream>>>(xb, 2048, wqab, wqa_b, qn, qn, 1536, 1536, 2048, 1.0f);
    gemm_kernel<0,0,0><<<dim3(64, 5),  blk, 0, stream>>>(xb, 2048, wkvab, wkva_b, kvn, 4096, 576, 2048, 1.0f);
    rmsnorm_kernel<<<4096, blk, 0, stream>>>(qn, qnw, 1536, 1536);
    rmsnorm_kernel<<<4096, blk, 0, stream>>>(kvn, kvnw, 512, 576);
    rope_kpe_kernel<<<512, blk, 0, stream>>>(kvn, fcos, fsin, kpe);

    // q projection: BOTH head groups in one 768-block dispatch
    gemm_lds_kernel<0><<<dim3(32, 24), blk, 0, stream>>>(qn, 1536, wqbb, wqb_b, qbA, qbB, 1536, 3072, 1536, SCALE);
    rope_q_kernel<<<4096, blk, 0, stream>>>(qbA, fcos, fsin);
    rope_q_kernel<<<4096, blk, 0, stream>>>(qbB, fcos, fsin);
    // kv projection: BOTH groups in one 1024-block dispatch (split at 2048)
    gemm_lds_kernel<0><<<dim3(32, 32), blk, 0, stream>>>(kvn, 576, wkvbw, wkvb_b, kvA, kvB, 2048, 4096, 512, 1.0f);

    // one attn dispatch: 512 uniform 33-iter blocks, 2 equal/CU throughout
    attn_kernel<1><<<dim3(16, 16, 2), blk, 0, stream>>>(qbA, qbB, kvA, kvB, kpe, ao, 0);

    gemm_lds_kernel<1><<<dim3(32, 16), blk, 0, stream>>>(ao, 2048, wob, wo_b, (float*)d_out, (float*)d_out, 2048, 2048, 2048, 1.0f);
  } else if (ws_size >= 111411200u) {
    // ---- round-4 path: bf16 weights, per-group attn (verified 635 us).
    u16* xb    = (u16*)(ws + 63963136);
    u16* wqab  = (u16*)(ws + 80740352);
    u16* wkvab = (u16*)(ws + 87031808);
    u16* wqbb  = (u16*)(ws + 89391104);
    u16* wkvbw = (u16*)(ws + 98828288);
    u16* wob   = (u16*)(ws + 103022592);

    cvt_kernel<<<2048, blk, 0, stream>>>(x,    xb,    1048576);
    cvt_kernel<<<1536, blk, 0, stream>>>(wqa,  wqab,   393216);
    cvt_kernel<<< 576, blk, 0, stream>>>(wkva, wkvab,  147456);
    cvt_kernel<<<2048, blk, 0, stream>>>(wqb,  wqbb,   589824);
    cvt_kernel<<<1024, blk, 0, stream>>>(wkvb, wkvbw,  262144);
    cvt_kernel<<<2048, blk, 0, stream>>>(wo,   wob,    524288);

    gemm_kernel<0,0,0><<<dim3(64, 12), blk, 0, stream>>>(xb, 2048, wqab, wqa_b, qn, 4096, 1536, 2048, 1.0f);
    gemm_kernel<0,0,0><<<dim3(64, 5),  blk, 0, stream>>>(xb, 2048, wkvab, wkva_b, kvn, 4096, 576, 2048, 1.0f);
    rmsnorm_kernel<<<4096, blk, 0, stream>>>(qn, qnw, 1536, 1536);
    rmsnorm_kernel<<<4096, blk, 0, stream>>>(kvn, kvnw, 512, 576);
    rope_kpe_kernel<<<512, blk, 0, stream>>>(kvn, fcos, fsin, kpe);

    for (int g = 0; g < 2; ++g) {
      const u16* wqb_g   = wqbb + (size_t)g * 1536 * 1536;
      const float* wqb_bg  = wqb_b + g * 1536;
      const u16* wkvb_g  = wkvbw + (size_t)g * 2048 * 512;
      const float* wkvb_bg = wkvb_b + g * 2048;
      gemm_kernel<0,0,0><<<dim3(64, 12), blk, 0, stream>>>(qn, 1536, wqb_g, wqb_bg, qbA, 4096, 1536, 1536, SCALE);
      rope_q_kernel<<<4096, blk, 0, stream>>>(qbA, fcos, fsin);
      gemm_kernel<0,0,0><<<dim3(64, 16), blk, 0, stream>>>(kvn, 576, wkvb_g, wkvb_bg, kvB, 4096, 2048, 512, 1.0f);
      attn_kernel<0><<<dim3(32, 8, 2), blk, 0, stream>>>(qbA, qbA, kvB, kvB, kpe, ao, g * 8);
    }

    gemm_kernel<0,0,1><<<dim3(64, 16), blk, 0, stream>>>(ao, 2048, wob, wo_b, (float*)d_out, 4096, 2048, 2048, 1.0f);
  } else {
    // ---- legacy path: fp32 weights converted in-loop (round-2).
    gemm_kernel<1,1,0><<<dim3(64, 12), blk, 0, stream>>>(x, 2048, wqa, wqa_b, qn, 4096, 1536, 2048, 1.0f);
    gemm_kernel<1,1,0><<<dim3(64, 5),  blk, 0, stream>>>(x, 2048, wkva, wkva_b, kvn, 4096, 576, 2048, 1.0f);
    rmsnorm_kernel<<<4096, blk, 0, stream>>>(qn, qnw, 1536, 1536);
    rmsnorm_kernel<<<4096, blk, 0, stream>>>(kvn, kvnw, 512, 576);
    rope_kpe_kernel<<<512, blk, 0, stream>>>(kvn, fcos, fsin, kpe);

    for (int g = 0; g < 2; ++g) {
      const float* wqb_g   = wqb + (size_t)g * 1536 * 1536;
      const float* wqb_bg  = wqb_b + g * 1536;
      const float* wkvb_g  = wkvb + (size_t)g * 2048 * 512;
      const float* wkvb_bg = wkvb_b + g * 2048;
      gemm_kernel<0,1,0><<<dim3(64, 12), blk, 0, stream>>>(qn, 1536, wqb_g, wqb_bg, qbA, 4096, 1536, 1536, SCALE);
      rope_q_kernel<<<4096, blk, 0, stream>>>(qbA, fcos, fsin);
      gemm_kernel<0,1,0><<<dim3(64, 16), blk, 0, stream>>>(kvn, 576, wkvb_g, wkvb_bg, kvB, 4096, 2048, 512, 1.0f);
      attn_kernel<0><<<dim3(32, 8, 2), blk, 0, stream>>>(qbA, qbA, kvB, kvB, kpe, ao, g * 8);
    }

    gemm_kernel<0,1,1><<<dim3(64, 16), blk, 0, stream>>>(ao, 2048, wo, wo_b, (float*)d_out, 4096, 2048, 2048, 1.0f);
  }
}

// Round 14
// 527.681 us; speedup vs baseline: 1.0672x; 1.0181x over previous
//
#include <hip/hip_runtime.h>

// MLA prefill: B=2, S=2048, DIM=2048, NH=16, Q_LORA=1536, KV_LORA=512,
// NOPE=128, ROPE=64, VHD=128, QK_HD=192.
// I/O dtype: FP32. Internal: bf16 MFMA.
//
// Round-14: launch-count harvest. GEMMs (r9/r10) and attn (r11-r13) are
// both at structural plateaus; the remaining slack is 6 cvt + 2 rope_q
// dispatches (~45-55us for ~23us of ideal HBM traffic): inter-dispatch
// gaps + tiny grids (wkva cvt = 576 blocks = 28% CU coverage). Merged:
// cvt6_kernel (one dispatch, grid (512,6), per-segment grid-stride) and
// rope_q2_kernel (grid (4096,2), y selects qbA/qbB). GEMM + attn are
// byte-identical to r13 (537.2us best; setprio kept, neutral-positive).
//
// WS plan (merged path, high-water 123,994,112 B):
//   qn    @ 0           [4096,1536]
//   kvn   @ 12,582,912  [4096, 576]  (cols 512..575 raw pe)
//   kpe   @ 17,301,504  [4096,  64]
//   qbA   @ 17,825,792  [4096,1536]  heads 0..7, pre-scaled by SCALE
//   kvB   @ 30,408,704  [4096,2048]  heads 8..15 (k_nope128|v128)
//   ao    @ 47,185,920  [4096,2048]
//   xb    @ 63,963,136  [4096,2048]  bf16 of x;  kvA reuses this slot
//   wqab  @ 80,740,352  [1536,2048]  bf16 weights
//   wkvab @ 87,031,808  [576,2048]
//   wqbb  @ 89,391,104  [2*1536,1536]
//   wkvbw @ 98,828,288  [2*2048,512]
//   wob   @103,022,592  [2048,2048]
//   qbB   @111,411,200  [4096,1536]  heads 8..15
// Fallbacks: ws>=111,411,200 -> round-4 path; else round-2 legacy path.

typedef __bf16 bf16x8 __attribute__((ext_vector_type(8)));
typedef float f32x4 __attribute__((ext_vector_type(4)));
typedef unsigned short u16;

#define SEQ 2048
#define SCALE 0.07216878364870323f  // 192^-0.5
#define NEGBIG -30000.0f            // expf underflows to exactly 0

__device__ __forceinline__ float b2f(u16 u) {
  union { unsigned u; float f; } c; c.u = ((unsigned)u) << 16; return c.f;
}
__device__ __forceinline__ u16 f2b(float f) {  // RNE fp32->bf16
  union { float f; unsigned u; } c; c.f = f;
  unsigned r = (c.u + 0x7fffu + ((c.u >> 16) & 1u)) >> 16;
  return (u16)r;
}
__device__ __forceinline__ uint4 pack8(float4 a, float4 b) {
  union { uint4 v; u16 e[8]; } t;
  t.e[0] = f2b(a.x); t.e[1] = f2b(a.y); t.e[2] = f2b(a.z); t.e[3] = f2b(a.w);
  t.e[4] = f2b(b.x); t.e[5] = f2b(b.y); t.e[6] = f2b(b.z); t.e[7] = f2b(b.w);
  return t.v;
}

// async 16B global -> LDS (HW writes lane's 16B to ldsbase + lane*16)
#define GLOAD_LDS16(gsrc, ldst)                                              \
  __builtin_amdgcn_global_load_lds(                                          \
      (const __attribute__((address_space(1))) unsigned int*)(gsrc),         \
      (__attribute__((address_space(3))) unsigned int*)(ldst), 16, 0, 0)

// ---------------------------------------------------------------------------
// fp32 -> bf16 bulk convert (n8 = element_count / 8). Single-segment form
// (fallback paths).
// ---------------------------------------------------------------------------
__global__ void cvt_kernel(const float* __restrict__ src, u16* __restrict__ dst,
                           long n8) {
  long i = (long)blockIdx.x * 256 + threadIdx.x;
  long stride = (long)gridDim.x * 256;
  for (; i < n8; i += stride) {
    const float4* s = (const float4*)(src + i * 8);
    float4 a = s[0], b = s[1];
    *(uint4*)(dst + i * 8) = pack8(a, b);
  }
}

// ---------------------------------------------------------------------------
// r14: all six fp32->bf16 conversions in ONE dispatch. blockIdx.y selects
// the segment; each y-slice grid-strides its own n8. Saturates all CUs
// (the old per-tensor launches left most CUs idle on small tensors and
// paid 5 inter-dispatch gaps).
// ---------------------------------------------------------------------------
__global__ void cvt6_kernel(
    const float* __restrict__ s0, u16* __restrict__ d0, long n0,
    const float* __restrict__ s1, u16* __restrict__ d1, long n1,
    const float* __restrict__ s2, u16* __restrict__ d2, long n2,
    const float* __restrict__ s3, u16* __restrict__ d3, long n3,
    const float* __restrict__ s4, u16* __restrict__ d4, long n4,
    const float* __restrict__ s5, u16* __restrict__ d5, long n5) {
  const float* src; u16* dst; long n8;
  switch (blockIdx.y) {
    case 0: src = s0; dst = d0; n8 = n0; break;
    case 1: src = s1; dst = d1; n8 = n1; break;
    case 2: src = s2; dst = d2; n8 = n2; break;
    case 3: src = s3; dst = d3; n8 = n3; break;
    case 4: src = s4; dst = d4; n8 = n4; break;
    default: src = s5; dst = d5; n8 = n5; break;
  }
  long i = (long)blockIdx.x * 256 + threadIdx.x;
  long stride = (long)gridDim.x * 256;
  for (; i < n8; i += stride) {
    const float4* s = (const float4*)(src + i * 8);
    float4 a = s[0], b = s[1];
    *(uint4*)(dst + i * 8) = pack8(a, b);
  }
}

// ---------------------------------------------------------------------------
// gemm_lds (r7-verified structure): out[4096,Ntot] = X @ W^T + bias, split
// across two destination buffers at col N0 (out0 cols [0,N0), stride N0;
// out1 cols [N0,Ntot), stride Ntot-N0). Requires N%128==0, K%64==0.
// 128x128 tile, BK=64, 4 waves 2x2 (acc 4x4), double-buffered
// global_load_lds staging, ONE barrier per K-step.
// LDS: XOR-swizzled LDS[r][c ^ ((r&7)*8)] = M[r][k0+c] via linear
// gload_lds dest + pre-swizzled global source col ((lane&7)^(lane>>3))*8;
// fragment ds_read applies the same XOR (identity round-trip).
// ---------------------------------------------------------------------------
template <int OF>
__global__ __launch_bounds__(256) void gemm_lds_kernel(
    const u16* __restrict__ X, int lda, const u16* __restrict__ W,
    const float* __restrict__ bias, void* __restrict__ out0,
    void* __restrict__ out1, int N0, int Ntot, int K, float oscale) {
  __shared__ alignas(16) u16 As[2][128 * 64];
  __shared__ alignas(16) u16 Bs[2][128 * 64];
  const int tid = threadIdx.x;
  const int wave = tid >> 6, lane = tid & 63;
  const int quad = lane >> 4, l16 = lane & 15;
  const int wr = (wave >> 1) * 64, wc = (wave & 1) * 64;
  const int bm = blockIdx.x * 128, bn = blockIdx.y * 128;
  const int srow0 = wave * 32 + (lane >> 3);          // + p*8
  const int gcol = ((lane & 7) ^ (lane >> 3)) * 8;    // pre-swizzled source col

  f32x4 acc[4][4] = {};

  auto stage = [&](int buf, int k0) {
#pragma unroll
    for (int p = 0; p < 4; ++p) {
      int row = srow0 + p * 8;
      const u16* ga = X + (size_t)(bm + row) * lda + k0 + gcol;
      const u16* gb = W + (size_t)(bn + row) * K + k0 + gcol;
      char* la = (char*)(&As[buf][0]) + (wave * 4 + p) * 1024;
      char* lb = (char*)(&Bs[buf][0]) + (wave * 4 + p) * 1024;
      GLOAD_LDS16(ga, la);
      GLOAD_LDS16(gb, lb);
    }
  };

  const int nk = K >> 6;
  stage(0, 0);
  int cur = 0;
  for (int kt = 0; kt < nk; ++kt) {
    __syncthreads();  // vmcnt drain: buf[cur] staged; prev readers of buf[cur^1] done
    if (kt + 1 < nk) stage(cur ^ 1, (kt + 1) * 64);  // flies under MFMA below
    const u16* as = &As[cur][0];
    const u16* bs = &Bs[cur][0];
#pragma unroll
    for (int kk = 0; kk < 64; kk += 32) {
      const int cs = (kk + quad * 8) ^ ((l16 & 7) * 8);
      bf16x8 a[4], b[4];
#pragma unroll
      for (int i = 0; i < 4; ++i)
        a[i] = *(const bf16x8*)(as + (wr + i * 16 + l16) * 64 + cs);
#pragma unroll
      for (int j = 0; j < 4; ++j)
        b[j] = *(const bf16x8*)(bs + (wc + j * 16 + l16) * 64 + cs);
#pragma unroll
      for (int i = 0; i < 4; ++i)
#pragma unroll
        for (int j = 0; j < 4; ++j)
          acc[i][j] = __builtin_amdgcn_mfma_f32_16x16x32_bf16(a[i], b[j], acc[i][j], 0, 0, 0);
    }
    cur ^= 1;
  }

  const int N1 = Ntot - N0;
#pragma unroll
  for (int i = 0; i < 4; ++i)
#pragma unroll
    for (int j = 0; j < 4; ++j) {
      int col = bn + wc + j * 16 + l16;
      float bv = bias[col];
#pragma unroll
      for (int r = 0; r < 4; ++r) {
        int row = bm + wr + i * 16 + quad * 4 + r;
        float v = (acc[i][j][r] + bv) * oscale;
        if (OF) {
          ((float*)out0)[(size_t)row * Ntot + col] = v;
        } else if (col < N0) {
          ((u16*)out0)[(size_t)row * N0 + col] = f2b(v);
        } else {
          ((u16*)out1)[(size_t)row * N1 + (col - N0)] = f2b(v);
        }
      }
    }
}

// ---------------------------------------------------------------------------
// Legacy GEMM: out[M,N] = (X[M,K] @ W[N,K]^T + bias[N]) * oscale
// XF/WF: 1 = fp32 source (convert at LDS store), 0 = bf16. OF: 1 = fp32 out.
// 64x128 tile, waves 1x4, register prefetch. kvn (N=576) + fallback paths.
// ---------------------------------------------------------------------------
template <int XF, int WF, int OF>
__global__ __launch_bounds__(256, 3) void gemm_kernel(
    const void* __restrict__ X, int lda, const void* __restrict__ W,
    const float* __restrict__ bias, void* __restrict__ out,
    int M, int N, int K, float oscale) {
  constexpr int LDT = 72;
  __shared__ alignas(16) u16 As[64 * LDT];
  __shared__ alignas(16) u16 Bs[128 * LDT];
  const int tid = threadIdx.x;
  const int wave = tid >> 6, lane = tid & 63;
  const int quad = lane >> 4, l16 = lane & 15;
  const int bm = blockIdx.x * 64, bn = blockIdx.y * 128;
  const int wn = wave * 32;
  const int srow = tid >> 3;           // 0..31
  const int scol = (tid & 7) * 8;      // 0..56

  f32x4 acc[4][2] = {};

  float4 pa32[2][2], pb32[4][2];
  uint4  pa16[2],    pb16[4];

  auto load_tile = [&](int k0) {
#pragma unroll
    for (int p = 0; p < 2; ++p) {
      size_t off = (size_t)(bm + srow + p * 32) * lda + k0 + scol;
      if (XF) {
        const float* s = (const float*)X + off;
        pa32[p][0] = *(const float4*)s;
        pa32[p][1] = *(const float4*)(s + 4);
      } else {
        pa16[p] = *(const uint4*)((const u16*)X + off);
      }
    }
#pragma unroll
    for (int p = 0; p < 4; ++p) {
      int n = bn + srow + p * 32;
      size_t off = (size_t)n * K + k0 + scol;
      if (WF) {
        if (n < N) {
          const float* s = (const float*)W + off;
          pb32[p][0] = *(const float4*)s;
          pb32[p][1] = *(const float4*)(s + 4);
        } else {
          pb32[p][0] = make_float4(0.f, 0.f, 0.f, 0.f);
          pb32[p][1] = make_float4(0.f, 0.f, 0.f, 0.f);
        }
      } else {
        if (n < N) pb16[p] = *(const uint4*)((const u16*)W + off);
        else { pb16[p].x = pb16[p].y = pb16[p].z = pb16[p].w = 0u; }
      }
    }
  };

  load_tile(0);
  for (int k0 = 0; k0 < K; k0 += 64) {
    __syncthreads();  // previous iteration's LDS readers done
#pragma unroll
    for (int p = 0; p < 2; ++p) {
      uint4 v;
      if (XF) v = pack8(pa32[p][0], pa32[p][1]); else v = pa16[p];
      *(uint4*)(&As[(srow + p * 32) * LDT + scol]) = v;
    }
#pragma unroll
    for (int p = 0; p < 4; ++p) {
      uint4 v;
      if (WF) v = pack8(pb32[p][0], pb32[p][1]); else v = pb16[p];
      *(uint4*)(&Bs[(srow + p * 32) * LDT + scol]) = v;
    }
    __syncthreads();  // also the compiler fence for the u16->bf16x8 pun
    if (k0 + 64 < K) load_tile(k0 + 64);  // latency hidden by MFMA below

#pragma unroll
    for (int kk = 0; kk < 64; kk += 32) {
      bf16x8 a[4], b[2];
#pragma unroll
      for (int i = 0; i < 4; ++i)
        a[i] = *(const bf16x8*)(&As[(i * 16 + l16) * LDT + kk + quad * 8]);
#pragma unroll
      for (int j = 0; j < 2; ++j)
        b[j] = *(const bf16x8*)(&Bs[(wn + j * 16 + l16) * LDT + kk + quad * 8]);
#pragma unroll
      for (int i = 0; i < 4; ++i)
#pragma unroll
        for (int j = 0; j < 2; ++j)
          acc[i][j] = __builtin_amdgcn_mfma_f32_16x16x32_bf16(a[i], b[j], acc[i][j], 0, 0, 0);
    }
  }

#pragma unroll
  for (int i = 0; i < 4; ++i)
#pragma unroll
    for (int j = 0; j < 2; ++j) {
      int col = bn + wn + j * 16 + l16;
      if (col < N) {
        float bv = bias[col];
#pragma unroll
        for (int r = 0; r < 4; ++r) {
          int row = bm + i * 16 + quad * 4 + r;
          float v = (acc[i][j][r] + bv) * oscale;
          if (OF) ((float*)out)[(size_t)row * N + col] = v;
          else    ((u16*)out)[(size_t)row * N + col] = f2b(v);
        }
      }
    }
}

// ---------------------------------------------------------------------------
__global__ void rmsnorm_kernel(u16* x, const float* __restrict__ w,
                               int C, int stride) {
  size_t base = (size_t)blockIdx.x * stride;
  float s = 0.f;
  for (int c = threadIdx.x; c < C; c += 256) { float v = b2f(x[base + c]); s += v * v; }
#pragma unroll
  for (int off = 32; off > 0; off >>= 1) s += __shfl_xor(s, off, 64);
  __shared__ float red[4];
  if ((threadIdx.x & 63) == 0) red[threadIdx.x >> 6] = s;
  __syncthreads();
  float tot = red[0] + red[1] + red[2] + red[3];
  float scale = rsqrtf(tot / (float)C + 1e-6f);
  for (int c = threadIdx.x; c < C; c += 256)
    x[base + c] = f2b(b2f(x[base + c]) * scale * w[c]);
}

// ---------------------------------------------------------------------------
__global__ void rope_kpe_kernel(const u16* __restrict__ kvn,
                                const float* __restrict__ fcos,
                                const float* __restrict__ fsin,
                                u16* __restrict__ kpe) {
  int idx = blockIdx.x * 256 + threadIdx.x;  // token*32 + i
  int t = idx >> 5, i = idx & 31;
  int s = t & (SEQ - 1);
  float c = fcos[s * 32 + i], sn = fsin[s * 32 + i];
  float xr = b2f(kvn[(size_t)t * 576 + 512 + 2 * i]);
  float xi = b2f(kvn[(size_t)t * 576 + 512 + 2 * i + 1]);
  kpe[(size_t)t * 64 + 2 * i]     = f2b(xr * c - xi * sn);
  kpe[(size_t)t * 64 + 2 * i + 1] = f2b(xr * sn + xi * c);
}

// ---------------------------------------------------------------------------
// In-place rope on q_pe, layout [4096 tokens, 8 heads x 192].
// Single-buffer form (fallback paths).
// ---------------------------------------------------------------------------
__global__ void rope_q_kernel(u16* q, const float* __restrict__ fcos,
                              const float* __restrict__ fsin) {
  int idx = blockIdx.x * 256 + threadIdx.x;  // t*256 + h*32 + i
  int t = idx >> 8, h = (idx >> 5) & 7, i = idx & 31;
  int s = t & (SEQ - 1);
  float c = fcos[s * 32 + i], sn = fsin[s * 32 + i];
  size_t base = (size_t)t * 1536 + h * 192 + 128 + 2 * i;
  float xr = b2f(q[base]), xi = b2f(q[base + 1]);
  q[base]     = f2b(xr * c - xi * sn);
  q[base + 1] = f2b(xr * sn + xi * c);
}

// r14: both head-groups' rope in one dispatch (blockIdx.y selects buffer).
__global__ void rope_q2_kernel(u16* qA, u16* qB, const float* __restrict__ fcos,
                               const float* __restrict__ fsin) {
  u16* q = blockIdx.y ? qB : qA;
  int idx = blockIdx.x * 256 + threadIdx.x;  // t*256 + h*32 + i
  int t = idx >> 8, h = (idx >> 5) & 7, i = idx & 31;
  int s = t & (SEQ - 1);
  float c = fcos[s * 32 + i], sn = fsin[s * 32 + i];
  size_t base = (size_t)t * 1536 + h * 192 + 128 + 2 * i;
  float xr = b2f(q[base]), xi = b2f(q[base + 1]);
  q[base]     = f2b(xr * c - xi * sn);
  q[base + 1] = f2b(xr * sn + xi * c);
}

// ---------------------------------------------------------------------------
// Flash attention (causal).
// PAIRED=1 (merged path): grid (16,16,2) = 512 uniform blocks, each
// processes q-tiles {31-x, x} = exactly 33 K-tile iters; CU co-residents
// have EQUAL length -> sustained 2-residency (round-6 verified).
// PAIRED=0 (fallbacks): grid (32,8,2), complementary cross-batch mapping.
// r11: P-fence is compiler-only (Ps wave-private; keeps prefetch in flight).
// r13: s_setprio(1) around QK and PV MFMA clusters (neutral-positive).
// ---------------------------------------------------------------------------
template <int PAIRED>
__global__ __launch_bounds__(256, 2) void attn_kernel(
    const u16* __restrict__ Q0,   // [4096, 1536] heads 0..7 (pre-scaled)
    const u16* __restrict__ Q1,   // [4096, 1536] heads 8..15
    const u16* __restrict__ KV0,  // [4096, 2048] heads 0..7 (k_nope|v)
    const u16* __restrict__ KV1,  // [4096, 2048] heads 8..15
    const u16* __restrict__ KPE,  // [4096, 64]
    u16* __restrict__ O,          // [4096, 2048]
    int hbase) {
  constexpr int LK = 200;
  constexpr int LP = 72;
  __shared__ alignas(16) u16 Ks[64 * LK];
  __shared__ alignas(16) u16 Ps[64 * LP];
  __shared__ alignas(16) u16 Vs[128 * LP];  // swizzled V^T

  const int tid = threadIdx.x;
  const int wave = tid >> 6, lane = tid & 63;
  const int quad = lane >> 4, l16 = lane & 15;
  const int h = hbase + blockIdx.y;       // global head 0..15
  const int hl = h & 7;
  const u16* __restrict__ Q   = (h & 8) ? Q1  : Q0;
  const u16* __restrict__ KVB = (h & 8) ? KV1 : KV0;
  const size_t tok0 = (size_t)blockIdx.z * SEQ;

  auto process = [&](int qt) {
    const int q0 = qt * 64;
    bf16x8 qf[6];
    {
      const u16* qp = Q + (tok0 + q0 + wave * 16 + l16) * 1536 + hl * 192 + quad * 8;
#pragma unroll
      for (int c = 0; c < 6; ++c) qf[c] = *(const bf16x8*)(qp + c * 32);
    }

    f32x4 o_acc[8] = {};
    float m_i[4], l_i[4];
#pragma unroll
    for (int r = 0; r < 4; ++r) { m_i[r] = NEGBIG; l_i[r] = 0.f; }

    const int nkt = qt + 1;
    uint4 kreg[6], vreg[4];
    auto load_tile = [&](int kt) {
      int k0 = kt * 64;
#pragma unroll
      for (int p = 0; p < 6; ++p) {
        int flat = tid + p * 256;
        int r = flat / 24, c8 = (flat % 24) * 8;
        const u16* src = (c8 < 128)
            ? (KVB + (tok0 + k0 + r) * 2048 + hl * 256 + c8)
            : (KPE + (tok0 + k0 + r) * 64 + (c8 - 128));
        kreg[p] = *(const uint4*)src;
      }
#pragma unroll
      for (int p = 0; p < 4; ++p) {
        int flat = tid + p * 256;
        int r = flat / 16, c8 = (flat % 16) * 8;
        vreg[p] = *(const uint4*)(KVB + (tok0 + k0 + r) * 2048 + hl * 256 + 128 + c8);
      }
    };

    load_tile(0);
    for (int kt = 0; kt < nkt; ++kt) {
      const int k0 = kt * 64;
      __syncthreads();  // B1: previous LDS readers done
#pragma unroll
      for (int p = 0; p < 6; ++p) {
        int flat = tid + p * 256;
        int r = flat / 24, c8 = (flat % 24) * 8;
        *(uint4*)(&Ks[r * LK + c8]) = kreg[p];
      }
#pragma unroll
      for (int p = 0; p < 4; ++p) {
        int flat = tid + p * 256;
        int r = flat / 16, c8 = (flat % 16) * 8;
        union { uint4 v4; u16 e[8]; } t;
        t.v4 = vreg[p];
        int rs = r >> 3, rl = r & 7;
#pragma unroll
        for (int j = 0; j < 8; ++j) {
          int n = c8 + j;
          Vs[n * LP + ((rs ^ ((n >> 3) & 7)) << 3) + rl] = t.e[j];
        }
      }
      __syncthreads();  // B2: Ks/Vs published to all waves
      if (kt + 1 < nkt) load_tile(kt + 1);

      f32x4 sc[4];
      __builtin_amdgcn_s_setprio(1);  // favor QK MFMA over co-resident block's staging
#pragma unroll
      for (int ni = 0; ni < 4; ++ni) {
        f32x4 a = {};
#pragma unroll
        for (int c = 0; c < 6; ++c) {
          bf16x8 kf = *(const bf16x8*)(&Ks[(ni * 16 + l16) * LK + c * 32 + quad * 8]);
          a = __builtin_amdgcn_mfma_f32_16x16x32_bf16(qf[c], kf, a, 0, 0, 0);
        }
        sc[ni] = a;
      }
      __builtin_amdgcn_s_setprio(0);

      const int qrow_base = q0 + wave * 16 + quad * 4;
      if (kt == nkt - 1) {  // only the diagonal tile needs the causal mask
#pragma unroll
        for (int ni = 0; ni < 4; ++ni) {
          int col = k0 + ni * 16 + l16;
#pragma unroll
          for (int r = 0; r < 4; ++r)
            if (col > qrow_base + r) sc[ni][r] = NEGBIG;
        }
      }

      float mloc[4];
#pragma unroll
      for (int r = 0; r < 4; ++r) mloc[r] = NEGBIG;
#pragma unroll
      for (int ni = 0; ni < 4; ++ni)
#pragma unroll
        for (int r = 0; r < 4; ++r) mloc[r] = fmaxf(mloc[r], sc[ni][r]);
#pragma unroll
      for (int off = 1; off < 16; off <<= 1)
#pragma unroll
        for (int r = 0; r < 4; ++r) mloc[r] = fmaxf(mloc[r], __shfl_xor(mloc[r], off, 64));

      float alpha[4], rsum[4];
#pragma unroll
      for (int r = 0; r < 4; ++r) {
        float mn = fmaxf(m_i[r], mloc[r]);
        alpha[r] = __expf(m_i[r] - mn);
        m_i[r] = mn;
        rsum[r] = 0.f;
      }
#pragma unroll
      for (int ni = 0; ni < 4; ++ni)
#pragma unroll
        for (int r = 0; r < 4; ++r) {
          float p = __expf(sc[ni][r] - m_i[r]);
          sc[ni][r] = p;
          rsum[r] += p;
        }
#pragma unroll
      for (int off = 1; off < 16; off <<= 1)
#pragma unroll
        for (int r = 0; r < 4; ++r) rsum[r] += __shfl_xor(rsum[r], off, 64);
#pragma unroll
      for (int r = 0; r < 4; ++r) l_i[r] = l_i[r] * alpha[r] + rsum[r];

#pragma unroll
      for (int ni = 0; ni < 4; ++ni)
#pragma unroll
        for (int r = 0; r < 4; ++r)
          Ps[(wave * 16 + quad * 4 + r) * LP + ni * 16 + l16] = f2b(sc[ni][r]);

      // Ps rows [wave*16, wave*16+16) are written and read by the SAME wave
      // only; HW DS ops are in-order per wave, so a compiler fence suffices
      // (and keeps the load_tile(kt+1) prefetch in flight through PV).
      asm volatile("" ::: "memory");

#pragma unroll
      for (int t8 = 0; t8 < 8; ++t8)
#pragma unroll
        for (int r = 0; r < 4; ++r) o_acc[t8][r] *= alpha[r];

      bf16x8 pf0 = *(const bf16x8*)(&Ps[(wave * 16 + l16) * LP + quad * 8]);
      bf16x8 pf1 = *(const bf16x8*)(&Ps[(wave * 16 + l16) * LP + 32 + quad * 8]);
      __builtin_amdgcn_s_setprio(1);  // favor PV MFMA cluster
#pragma unroll
      for (int ni = 0; ni < 8; ++ni) {
        int n0 = ni * 16 + l16;
        int sw = (n0 >> 3) & 7;
        bf16x8 vf0 = *(const bf16x8*)(&Vs[n0 * LP + ((quad ^ sw) << 3)]);
        bf16x8 vf1 = *(const bf16x8*)(&Vs[n0 * LP + (((4 + quad) ^ sw) << 3)]);
        o_acc[ni] = __builtin_amdgcn_mfma_f32_16x16x32_bf16(pf0, vf0, o_acc[ni], 0, 0, 0);
        o_acc[ni] = __builtin_amdgcn_mfma_f32_16x16x32_bf16(pf1, vf1, o_acc[ni], 0, 0, 0);
      }
      __builtin_amdgcn_s_setprio(0);
    }

#pragma unroll
    for (int ni = 0; ni < 8; ++ni) {
      int col = h * 128 + ni * 16 + l16;
#pragma unroll
      for (int r = 0; r < 4; ++r) {
        size_t row = tok0 + q0 + wave * 16 + quad * 4 + r;
        O[row * 2048 + col] = f2b(o_acc[ni][r] / l_i[r]);
      }
    }
  };

  if (PAIRED) {
    // Uniform 33 iters/block: long tile then short tile (round-6 verified).
    process(31 - (int)blockIdx.x);  // qt in [16,31]: 17..32 iters
    process((int)blockIdx.x);       // qt in [0,15]:  1..16 iters
  } else {
    // Complementary cross-batch pairing (round-2/4 verified).
    process(blockIdx.z == 0 ? (31 - (int)blockIdx.x) : (int)blockIdx.x);
  }
}

// ---------------------------------------------------------------------------
extern "C" void kernel_launch(void* const* d_in, const int* in_sizes, int n_in,
                              void* d_out, int out_size, void* d_ws, size_t ws_size,
                              hipStream_t stream) {
  const float* x      = (const float*)d_in[0];
  const float* fcos   = (const float*)d_in[1];
  const float* fsin   = (const float*)d_in[2];
  const float* wqa    = (const float*)d_in[3];
  const float* wqa_b  = (const float*)d_in[4];
  const float* qnw    = (const float*)d_in[5];
  const float* wqb    = (const float*)d_in[6];
  const float* wqb_b  = (const float*)d_in[7];
  const float* wkva   = (const float*)d_in[8];
  const float* wkva_b = (const float*)d_in[9];
  const float* kvnw   = (const float*)d_in[10];
  const float* wkvb   = (const float*)d_in[11];
  const float* wkvb_b = (const float*)d_in[12];
  const float* wo     = (const float*)d_in[13];
  const float* wo_b   = (const float*)d_in[14];

  char* ws = (char*)d_ws;
  u16* qn   = (u16*)(ws + 0);           // [4096,1536]
  u16* kvn  = (u16*)(ws + 12582912);    // [4096,576]
  u16* kpe  = (u16*)(ws + 17301504);    // [4096,64]
  u16* qbA  = (u16*)(ws + 17825792);    // [4096,1536] heads 0..7
  u16* kvB  = (u16*)(ws + 30408704);    // [4096,2048] heads 8..15
  u16* ao   = (u16*)(ws + 47185920);    // [4096,2048]

  dim3 blk(256);

  if (ws_size >= 123994112u) {
    // ---- merged path: r13 GEMM/attn + single cvt6 / rope_q2 dispatches.
    u16* xb    = (u16*)(ws + 63963136);   // [4096,2048] bf16 x; later kvA
    u16* kvA   = (u16*)(ws + 63963136);   // heads 0..7 (reuses xb slot)
    u16* wqab  = (u16*)(ws + 80740352);   // [1536,2048]
    u16* wkvab = (u16*)(ws + 87031808);   // [576,2048]
    u16* wqbb  = (u16*)(ws + 89391104);   // [2*1536,1536]
    u16* wkvbw = (u16*)(ws + 98828288);   // [2*2048,512]
    u16* wob   = (u16*)(ws + 103022592);  // [2048,2048]
    u16* qbB   = (u16*)(ws + 111411200);  // [4096,1536] heads 8..15

    // all six fp32->bf16 conversions in ONE dispatch (r14)
    cvt6_kernel<<<dim3(512, 6), blk, 0, stream>>>(
        x,    xb,    1048576,
        wqa,  wqab,   393216,
        wkva, wkvab,  147456,
        wqb,  wqbb,   589824,
        wkvb, wkvbw,  262144,
        wo,   wob,    524288);

    gemm_lds_kernel<0><<<dim3(32, 12), blk, 0, stream>>>(xb, 2048, wqab, wqa_b, qn, qn, 1536, 1536, 2048, 1.0f);
    gemm_kernel<0,0,0><<<dim3(64, 5),  blk, 0, stream>>>(xb, 2048, wkvab, wkva_b, kvn, 4096, 576, 2048, 1.0f);
    rmsnorm_kernel<<<4096, blk, 0, stream>>>(qn, qnw, 1536, 1536);
    rmsnorm_kernel<<<4096, blk, 0, stream>>>(kvn, kvnw, 512, 576);
    rope_kpe_kernel<<<512, blk, 0, stream>>>(kvn, fcos, fsin, kpe);

    // q projection: BOTH head groups in one 768-block dispatch
    gemm_lds_kernel<0><<<dim3(32, 24), blk, 0, stream>>>(qn, 1536, wqbb, wqb_b, qbA, qbB, 1536, 3072, 1536, SCALE);
    // both groups' rope in one dispatch (r14)
    rope_q2_kernel<<<dim3(4096, 2), blk, 0, stream>>>(qbA, qbB, fcos, fsin);
    // kv projection: BOTH groups in one 1024-block dispatch (split at 2048)
    gemm_lds_kernel<0><<<dim3(32, 32), blk, 0, stream>>>(kvn, 576, wkvbw, wkvb_b, kvA, kvB, 2048, 4096, 512, 1.0f);

    // one attn dispatch: 512 uniform 33-iter blocks, 2 equal/CU throughout
    attn_kernel<1><<<dim3(16, 16, 2), blk, 0, stream>>>(qbA, qbB, kvA, kvB, kpe, ao, 0);

    gemm_lds_kernel<1><<<dim3(32, 16), blk, 0, stream>>>(ao, 2048, wob, wo_b, (float*)d_out, (float*)d_out, 2048, 2048, 2048, 1.0f);
  } else if (ws_size >= 111411200u) {
    // ---- round-4 path: bf16 weights, per-group attn (verified 635 us).
    u16* xb    = (u16*)(ws + 63963136);
    u16* wqab  = (u16*)(ws + 80740352);
    u16* wkvab = (u16*)(ws + 87031808);
    u16* wqbb  = (u16*)(ws + 89391104);
    u16* wkvbw = (u16*)(ws + 98828288);
    u16* wob   = (u16*)(ws + 103022592);

    cvt_kernel<<<2048, blk, 0, stream>>>(x,    xb,    1048576);
    cvt_kernel<<<1536, blk, 0, stream>>>(wqa,  wqab,   393216);
    cvt_kernel<<< 576, blk, 0, stream>>>(wkva, wkvab,  147456);
    cvt_kernel<<<2048, blk, 0, stream>>>(wqb,  wqbb,   589824);
    cvt_kernel<<<1024, blk, 0, stream>>>(wkvb, wkvbw,  262144);
    cvt_kernel<<<2048, blk, 0, stream>>>(wo,   wob,    524288);

    gemm_kernel<0,0,0><<<dim3(64, 12), blk, 0, stream>>>(xb, 2048, wqab, wqa_b, qn, 4096, 1536, 2048, 1.0f);
    gemm_kernel<0,0,0><<<dim3(64, 5),  blk, 0, stream>>>(xb, 2048, wkvab, wkva_b, kvn, 4096, 576, 2048, 1.0f);
    rmsnorm_kernel<<<4096, blk, 0, stream>>>(qn, qnw, 1536, 1536);
    rmsnorm_kernel<<<4096, blk, 0, stream>>>(kvn, kvnw, 512, 576);
    rope_kpe_kernel<<<512, blk, 0, stream>>>(kvn, fcos, fsin, kpe);

    for (int g = 0; g < 2; ++g) {
      const u16* wqb_g   = wqbb + (size_t)g * 1536 * 1536;
      const float* wqb_bg  = wqb_b + g * 1536;
      const u16* wkvb_g  = wkvbw + (size_t)g * 2048 * 512;
      const float* wkvb_bg = wkvb_b + g * 2048;
      gemm_kernel<0,0,0><<<dim3(64, 12), blk, 0, stream>>>(qn, 1536, wqb_g, wqb_bg, qbA, 4096, 1536, 1536, SCALE);
      rope_q_kernel<<<4096, blk, 0, stream>>>(qbA, fcos, fsin);
      gemm_kernel<0,0,0><<<dim3(64, 16), blk, 0, stream>>>(kvn, 576, wkvb_g, wkvb_bg, kvB, 4096, 2048, 512, 1.0f);
      attn_kernel<0><<<dim3(32, 8, 2), blk, 0, stream>>>(qbA, qbA, kvB, kvB, kpe, ao, g * 8);
    }

    gemm_kernel<0,0,1><<<dim3(64, 16), blk, 0, stream>>>(ao, 2048, wob, wo_b, (float*)d_out, 4096, 2048, 2048, 1.0f);
  } else {
    // ---- legacy path: fp32 weights converted in-loop (round-2).
    gemm_kernel<1,1,0><<<dim3(64, 12), blk, 0, stream>>>(x, 2048, wqa, wqa_b, qn, 4096, 1536, 2048, 1.0f);
    gemm_kernel<1,1,0><<<dim3(64, 5),  blk, 0, stream>>>(x, 2048, wkva, wkva_b, kvn, 4096, 576, 2048, 1.0f);
    rmsnorm_kernel<<<4096, blk, 0, stream>>>(qn, qnw, 1536, 1536);
    rmsnorm_kernel<<<4096, blk, 0, stream>>>(kvn, kvnw, 512, 576);
    rope_kpe_kernel<<<512, blk, 0, stream>>>(kvn, fcos, fsin, kpe);

    for (int g = 0; g < 2; ++g) {
      const float* wqb_g   = wqb + (size_t)g * 1536 * 1536;
      const float* wqb_bg  = wqb_b + g * 1536;
      const float* wkvb_g  = wkvb + (size_t)g * 2048 * 512;
      const float* wkvb_bg = wkvb_b + g * 2048;
      gemm_kernel<0,1,0><<<dim3(64, 12), blk, 0, stream>>>(qn, 1536, wqb_g, wqb_bg, qbA, 4096, 1536, 1536, SCALE);
      rope_q_kernel<<<4096, blk, 0, stream>>>(qbA, fcos, fsin);
      gemm_kernel<0,1,0><<<dim3(64, 16), blk, 0, stream>>>(kvn, 576, wkvb_g, wkvb_bg, kvB, 4096, 2048, 512, 1.0f);
      attn_kernel<0><<<dim3(32, 8, 2), blk, 0, stream>>>(qbA, qbA, kvB, kvB, kpe, ao, g * 8);
    }

    gemm_kernel<0,1,1><<<dim3(64, 16), blk, 0, stream>>>(ao, 2048, wo, wo_b, (float*)d_out, 4096, 2048, 2048, 1.0f);
  }
}